// Round 1
// baseline (386.408 us; speedup 1.0000x reference)
//
#include <hip/hip_runtime.h>
#include <stdint.h>

// ---------------------------------------------------------------------------
// DS_MultiHeadLatentAttention on MI355X (gfx950), round 1.
// Pipeline (all bf16 MFMA, fp32 accumulate):
//   1. Qp   = queries @ Wq + bq          [4096,1024] bf16   (ws +0)
//   2. Lat  = keys    @ Wd + bd          [4096, 256] bf16   (ws +8M)
//   3. Kp   = Lat     @ Wk + bk          [4096,1024] bf16   (ws +10M)
//   4. VpT  = Lat     @ Wv + bv (transposed: [b][h*64+d][2048]) (ws +18M)
//   5. Attn = causal softmax(Q K^T / 8) V  [4096,1024] bf16 (ws +26M)
//   6. out  = Attn @ Wo + bo             [4096,1024] fp32 -> d_out
// Requires ws_size >= 34 MB.
// MFMA layouts (m89/m91/m120 verified): A/B frag = [lane&15][quad*8+j],
// C/D = row (lane>>4)*4+reg, col lane&15.
// ---------------------------------------------------------------------------

#define DM   1024
#define NH   16
#define DK   64
#define LL   2048
#define BB   2

typedef float  f32x4  __attribute__((ext_vector_type(4)));
typedef __bf16 bf16x8 __attribute__((ext_vector_type(8)));
typedef short  s16x8  __attribute__((ext_vector_type(8)));

__device__ __forceinline__ unsigned short f2bf(float f) {
    union { float f; unsigned int u; } v; v.f = f;
    return (unsigned short)((v.u + 0x7fffu + ((v.u >> 16) & 1u)) >> 16);
}
__device__ __forceinline__ unsigned int pack2(float a, float b) {
    return (unsigned int)f2bf(a) | ((unsigned int)f2bf(b) << 16);
}
__device__ __forceinline__ bf16x8 ld8(const unsigned short* p) {
    s16x8 s = *(const s16x8*)p;
    return __builtin_bit_cast(bf16x8, s);
}

// ---------------------------------------------------------------------------
// GEMM: C[M=4096, N] = A[4096, K] * W[K, N] + bias.  64x64 tile, BK=32.
// Each of 4 waves computes a 16x64 strip (4 MFMA accumulators).
// ---------------------------------------------------------------------------
template<bool A_BF16, bool C_BF16, bool C_TRANS>
__global__ __launch_bounds__(256)
void gemm_k(const void* __restrict__ Ap, const float* __restrict__ W,
            const float* __restrict__ bias, void* __restrict__ Cp,
            int K, int N) {
    __shared__ unsigned short As[64][32];      // [m][k]
    __shared__ unsigned short Bs[64 * 32];     // [n][k], 16B-chunk XOR swizzled

    const int m0   = blockIdx.y * 64;
    const int n0   = blockIdx.x * 64;
    const int t    = threadIdx.x;
    const int lane = t & 63;
    const int wv   = t >> 6;
    const int quad = lane >> 4;
    const int l15  = lane & 15;

    f32x4 acc[4] = {{0.f,0.f,0.f,0.f},{0.f,0.f,0.f,0.f},
                    {0.f,0.f,0.f,0.f},{0.f,0.f,0.f,0.f}};

    const int arow = t >> 2;            // 0..63
    const int ak0  = (t & 3) * 8;       // 0,8,16,24
    const int bn   = t & 63;            // B staging: n within tile
    const int bk0  = wv * 8;            // B staging: k chunk base
    const int bpos = bn * 32 + ((wv ^ ((bn >> 1) & 3)) * 8);  // swizzled slot

    for (int kk = 0; kk < K; kk += 32) {
        // -- global loads into regs (no LDS deps) --
        uint4 apk;
        if (A_BF16) {
            const unsigned short* A16 = (const unsigned short*)Ap;
            apk = *(const uint4*)(A16 + (size_t)(m0 + arow) * K + kk + ak0);
        } else {
            const float* A32 = (const float*)Ap + (size_t)(m0 + arow) * K + kk + ak0;
            float4 f0 = *(const float4*)(A32);
            float4 f1 = *(const float4*)(A32 + 4);
            apk.x = pack2(f0.x, f0.y); apk.y = pack2(f0.z, f0.w);
            apk.z = pack2(f1.x, f1.y); apk.w = pack2(f1.z, f1.w);
        }
        const float* Wp = W + (size_t)(kk + bk0) * N + n0 + bn;
        float w0 = Wp[0];
        float w1 = Wp[(size_t)N];
        float w2 = Wp[(size_t)2 * N];
        float w3 = Wp[(size_t)3 * N];
        float w4 = Wp[(size_t)4 * N];
        float w5 = Wp[(size_t)5 * N];
        float w6 = Wp[(size_t)6 * N];
        float w7 = Wp[(size_t)7 * N];
        uint4 bpk;
        bpk.x = pack2(w0, w1); bpk.y = pack2(w2, w3);
        bpk.z = pack2(w4, w5); bpk.w = pack2(w6, w7);

        __syncthreads();   // previous iteration's frag reads done
        *(uint4*)(&As[arow][ak0]) = apk;
        *(uint4*)(&Bs[bpos])      = bpk;
        __syncthreads();

        bf16x8 a = ld8(&As[wv * 16 + l15][quad * 8]);
        #pragma unroll
        for (int nt = 0; nt < 4; ++nt) {
            const int nl = nt * 16 + l15;
            bf16x8 b = ld8(&Bs[nl * 32 + ((quad ^ ((nl >> 1) & 3)) * 8)]);
            acc[nt] = __builtin_amdgcn_mfma_f32_16x16x32_bf16(a, b, acc[nt], 0, 0, 0);
        }
    }

    #pragma unroll
    for (int nt = 0; nt < 4; ++nt) {
        const int col = n0 + nt * 16 + l15;
        const float bv = bias[col];
        #pragma unroll
        for (int r = 0; r < 4; ++r) {
            const int row = m0 + wv * 16 + quad * 4 + r;
            const float v = acc[nt][r] + bv;
            if (C_TRANS) {
                // [b][h*64+d][l]: ((row>>11)*1024 + col)*2048 + (row&2047)
                ((unsigned short*)Cp)[((size_t)(row >> 11) * 1024 + col) * (size_t)LL
                                      + (row & (LL - 1))] = f2bf(v);
            } else if (C_BF16) {
                ((unsigned short*)Cp)[(size_t)row * N + col] = f2bf(v);
            } else {
                ((float*)Cp)[(size_t)row * N + col] = v;
            }
        }
    }
}

// ---------------------------------------------------------------------------
// Causal flash attention. Block = 256 thr (4 waves), 64 q-rows/block
// (16 per wave), key chunks of 32. Online softmax, P via LDS transpose.
// ---------------------------------------------------------------------------
__global__ __launch_bounds__(256)
void attn_k(const unsigned short* __restrict__ Qp,
            const unsigned short* __restrict__ Kp,
            const unsigned short* __restrict__ VpT,
            unsigned short* __restrict__ Op) {
    __shared__ unsigned short Ks[32][72];       // [key][k], +8 pad
    __shared__ unsigned short VsT[64][32];      // [d][key]
    __shared__ unsigned short Ps[4][16][32];    // per-wave P transpose buffer

    const int q0   = blockIdx.x * 64;
    const int h    = blockIdx.y;
    const int b    = blockIdx.z;
    const int t    = threadIdx.x;
    const int lane = t & 63;
    const int wv   = t >> 6;
    const int quad = lane >> 4;
    const int l15  = lane & 15;

    // Q fragments, loop-invariant (rows wv*16 + l15)
    bf16x8 aq0, aq1;
    {
        const unsigned short* q = Qp + (size_t)(b * LL + q0 + wv * 16 + l15) * DM + h * DK;
        aq0 = ld8(q + quad * 8);
        aq1 = ld8(q + 32 + quad * 8);
    }

    f32x4 acc[4] = {{0.f,0.f,0.f,0.f},{0.f,0.f,0.f,0.f},
                    {0.f,0.f,0.f,0.f},{0.f,0.f,0.f,0.f}};
    float mrow[4] = {-__builtin_inff(), -__builtin_inff(),
                     -__builtin_inff(), -__builtin_inff()};
    float lrow[4] = {0.f, 0.f, 0.f, 0.f};
    const int rowb = q0 + wv * 16 + quad * 4;   // +r = within-batch q index

    const int kkey = t >> 3;                    // 0..31
    const int kk0  = (t & 7) * 8;
    const int vd   = t >> 2;                    // 0..63
    const int vk0  = (t & 3) * 8;

    const int nch = q0 / 32 + 2;
    for (int c = 0; c < nch; ++c) {
        const int kt = c * 32;
        const uint4 kpk = *(const uint4*)(Kp + (size_t)(b * LL + kt + kkey) * DM + h * DK + kk0);
        const uint4 vpk = *(const uint4*)(VpT + ((size_t)(b * NH + h) * DK + vd) * LL + kt + vk0);
        __syncthreads();                        // prev PV reads done
        *(uint4*)(&Ks[kkey][kk0]) = kpk;
        *(uint4*)(&VsT[vd][vk0])  = vpk;
        __syncthreads();

        // S = Q K^T  (two 16-key subtiles, K-dim 64 = 2 MFMA steps each)
        f32x4 s0 = {0.f,0.f,0.f,0.f}, s1 = {0.f,0.f,0.f,0.f};
        {
            bf16x8 bk0f = ld8(&Ks[l15][quad * 8]);
            s0 = __builtin_amdgcn_mfma_f32_16x16x32_bf16(aq0, bk0f, s0, 0, 0, 0);
            bf16x8 bk0s = ld8(&Ks[l15][32 + quad * 8]);
            s0 = __builtin_amdgcn_mfma_f32_16x16x32_bf16(aq1, bk0s, s0, 0, 0, 0);
            bf16x8 bk1f = ld8(&Ks[16 + l15][quad * 8]);
            s1 = __builtin_amdgcn_mfma_f32_16x16x32_bf16(aq0, bk1f, s1, 0, 0, 0);
            bf16x8 bk1s = ld8(&Ks[16 + l15][32 + quad * 8]);
            s1 = __builtin_amdgcn_mfma_f32_16x16x32_bf16(aq1, bk1s, s1, 0, 0, 0);
        }

        const int c0 = kt + l15;
        const int c1 = kt + 16 + l15;
        float pv0[4], pv1[4];
        #pragma unroll
        for (int r = 0; r < 4; ++r) {
            const int row   = rowb + r;
            const bool msk0 = c0 > row;
            const bool msk1 = c1 > row;
            const float v0  = s0[r] * 0.125f;   // 1/sqrt(64)
            const float v1  = s1[r] * 0.125f;
            float x = fmaxf(msk0 ? -__builtin_inff() : v0,
                            msk1 ? -__builtin_inff() : v1);
            #pragma unroll
            for (int off = 1; off < 16; off <<= 1)
                x = fmaxf(x, __shfl_xor(x, off, 64));
            const float mnew  = fmaxf(mrow[r], x);          // finite after chunk 0
            const float alpha = __expf(mrow[r] - mnew);     // exp(-inf)=0 first time
            const float p0 = msk0 ? 0.f : __expf(v0 - mnew);
            const float p1 = msk1 ? 0.f : __expf(v1 - mnew);
            float rs = p0 + p1;
            #pragma unroll
            for (int off = 1; off < 16; off <<= 1)
                rs += __shfl_xor(rs, off, 64);
            lrow[r] = lrow[r] * alpha + rs;
            mrow[r] = mnew;
            acc[0][r] *= alpha; acc[1][r] *= alpha;
            acc[2][r] *= alpha; acc[3][r] *= alpha;
            pv0[r] = p0; pv1[r] = p1;
        }

        // P (C-layout) -> LDS -> A-layout
        #pragma unroll
        for (int r = 0; r < 4; ++r) {
            Ps[wv][quad * 4 + r][l15]      = f2bf(pv0[r]);
            Ps[wv][quad * 4 + r][16 + l15] = f2bf(pv1[r]);
        }
        __syncthreads();

        bf16x8 ap = ld8(&Ps[wv][l15][quad * 8]);
        #pragma unroll
        for (int d = 0; d < 4; ++d) {
            bf16x8 bvf = ld8(&VsT[d * 16 + l15][quad * 8]);
            acc[d] = __builtin_amdgcn_mfma_f32_16x16x32_bf16(ap, bvf, acc[d], 0, 0, 0);
        }
    }

    #pragma unroll
    for (int d = 0; d < 4; ++d) {
        #pragma unroll
        for (int r = 0; r < 4; ++r) {
            const float v = acc[d][r] / lrow[r];
            Op[(size_t)(b * LL + rowb + r) * DM + h * DK + d * 16 + l15] = f2bf(v);
        }
    }
}

// ---------------------------------------------------------------------------
extern "C" void kernel_launch(void* const* d_in, const int* in_sizes, int n_in,
                              void* d_out, int out_size, void* d_ws, size_t ws_size,
                              hipStream_t stream) {
    const float* queries = (const float*)d_in[0];
    const float* keys    = (const float*)d_in[1];
    // d_in[2] = values: unused by the reference
    const float* Wq = (const float*)d_in[3];
    const float* bq = (const float*)d_in[4];
    const float* Wd = (const float*)d_in[5];
    const float* bd = (const float*)d_in[6];
    const float* Wk = (const float*)d_in[7];
    const float* bk = (const float*)d_in[8];
    const float* Wv = (const float*)d_in[9];
    const float* bv = (const float*)d_in[10];
    const float* Wo = (const float*)d_in[11];
    const float* bo = (const float*)d_in[12];

    char* ws = (char*)d_ws;
    unsigned short* Qp   = (unsigned short*)(ws);               //  8 MB
    unsigned short* Lat  = (unsigned short*)(ws + 8388608);     //  2 MB
    unsigned short* Kp   = (unsigned short*)(ws + 10485760);    //  8 MB
    unsigned short* VpT  = (unsigned short*)(ws + 18874368);    //  8 MB
    unsigned short* Attn = (unsigned short*)(ws + 27262976);    //  8 MB

    gemm_k<false, true, false><<<dim3(16, 64), 256, 0, stream>>>(queries, Wq, bq, Qp,  1024, 1024);
    gemm_k<false, true, false><<<dim3(4,  64), 256, 0, stream>>>(keys,    Wd, bd, Lat, 1024, 256);
    gemm_k<true,  true, false><<<dim3(16, 64), 256, 0, stream>>>(Lat,     Wk, bk, Kp,  256,  1024);
    gemm_k<true,  true, true ><<<dim3(16, 64), 256, 0, stream>>>(Lat,     Wv, bv, VpT, 256,  1024);
    attn_k<<<dim3(32, 16, 2), 256, 0, stream>>>(Qp, Kp, VpT, Attn);
    gemm_k<true, false, false><<<dim3(16, 64), 256, 0, stream>>>(Attn,    Wo, bo, d_out, 1024, 1024);
}

// Round 2
// 308.271 us; speedup vs baseline: 1.2535x; 1.2535x over previous
//
#include <hip/hip_runtime.h>
#include <stdint.h>

// ---------------------------------------------------------------------------
// DS_MultiHeadLatentAttention, round 2.
//  - GEMMs: m97-style 128x128 tile, BK=32, global_load_lds(16B) staging,
//    XOR chunk swizzle (2-way max bank aliasing), weights pre-transposed to
//    bf16 [N][K] by wtrans_k.
//  - Attention: 64-key chunks, fixed-shift softmax (no max reduction, no
//    rescale -- scores are O(6) sigma so exp2(s*0.125*log2e - 16) cannot
//    overflow and the 2^-16 factor cancels in normalization), per-wave P
//    buffer (no barrier for the C->A layout transpose), paired q-tiles
//    (j, 31-j) for uniform work (33 chunks/block).
// Workspace (34 MB, same footprint as round 1):
//   [0,8M)   Qp          [8M,16M)  Kp          [16M,24M) VpT
//   [24M,32M) Attn  (aliases WqT/WdT/WkT/WvT/Lat, all dead before attn runs)
//   [32M,34M) WoT
// ---------------------------------------------------------------------------

#define DM 1024
#define NH 16
#define DK 64
#define LL 2048

typedef float  f32x4  __attribute__((ext_vector_type(4)));
typedef __bf16 bf16x8 __attribute__((ext_vector_type(8)));
typedef short  s16x8  __attribute__((ext_vector_type(8)));

__device__ __forceinline__ unsigned short f2bf(float f) {
    union { float f; unsigned int u; } v; v.f = f;
    return (unsigned short)((v.u + 0x7fffu + ((v.u >> 16) & 1u)) >> 16);
}
__device__ __forceinline__ unsigned int pack2(float a, float b) {
    return (unsigned int)f2bf(a) | ((unsigned int)f2bf(b) << 16);
}
__device__ __forceinline__ bf16x8 ld8(const unsigned short* p) {
    s16x8 s = *(const s16x8*)p;
    return __builtin_bit_cast(bf16x8, s);
}
// async global->LDS, 16B per lane; LDS dest = wave-uniform base + lane*16
__device__ __forceinline__ void gl16(const void* g, void* l) {
    __builtin_amdgcn_global_load_lds((__attribute__((address_space(1))) void*)(g),
                                     (__attribute__((address_space(3))) void*)(l),
                                     16, 0, 0);
}
#define SWZ(r) (((r) ^ ((r) >> 2)) & 3)

// ---------------------------------------------------------------------------
// Weight transpose+convert: W [K,N] fp32 -> WT [N,K] bf16.
// ---------------------------------------------------------------------------
__global__ __launch_bounds__(256)
void wtrans_k(const float* __restrict__ W, unsigned short* __restrict__ WT,
              int K, int N) {
    __shared__ float tile[32][33];
    const int k0 = blockIdx.x * 32, n0 = blockIdx.y * 32;
    const int tx = threadIdx.x & 31, ty = threadIdx.x >> 5;
#pragma unroll
    for (int i = 0; i < 4; ++i)
        tile[ty + 8 * i][tx] = W[(size_t)(k0 + ty + 8 * i) * N + n0 + tx];
    __syncthreads();
#pragma unroll
    for (int i = 0; i < 4; ++i)
        WT[(size_t)(n0 + ty + 8 * i) * K + k0 + tx] = f2bf(tile[tx][ty + 8 * i]);
}

// ---------------------------------------------------------------------------
// GEMM: C[M,N] = A[M,K] @ BT[N,K]^T + bias. 128x128 tile, BK=32, 4 waves
// (2x2), each wave 4x4 accs of 16x16x32 MFMA.
// A_F32: A is fp32 (VALU pack staging); else bf16 via global_load_lds.
// OUT: 0 = bf16 row-major, 1 = fp32 row-major, 2 = bf16 [b][col][l] (VpT).
// ---------------------------------------------------------------------------
template<int A_F32, int OUT>
__global__ __launch_bounds__(256)
void gemm128_k(const void* __restrict__ Ap, const unsigned short* __restrict__ Bt,
               const float* __restrict__ bias, void* __restrict__ Cp,
               int K, int N) {
    __shared__ unsigned short As[128 * 32];   // 8 KB, [m][k], chunk-swizzled
    __shared__ unsigned short Bs[128 * 32];   // 8 KB, [n][k], chunk-swizzled

    const int t = threadIdx.x, lane = t & 63, wv = t >> 6;
    const int quad = lane >> 4, l15 = lane & 15;
    const int m0 = blockIdx.y * 128, n0 = blockIdx.x * 128;

    const int srow0 = wv * 32 + (lane >> 2);
    const int srow1 = srow0 + 16;
    const int sc = lane & 3;
    const int g0 = sc ^ SWZ(srow0);
    const int g1 = sc ^ SWZ(srow1);
    const unsigned short* gB0 = Bt + (size_t)(n0 + srow0) * K + g0 * 8;
    const unsigned short* gB1 = Bt + (size_t)(n0 + srow1) * K + g1 * 8;
    unsigned short* lB = Bs + wv * 1024;
    const unsigned short* gA0 = (const unsigned short*)Ap + (size_t)(m0 + srow0) * K + g0 * 8;
    const unsigned short* gA1 = (const unsigned short*)Ap + (size_t)(m0 + srow1) * K + g1 * 8;
    unsigned short* lA = As + wv * 1024;

    const int afr = t >> 1;
    const int ah = (t & 1) * 16;
    const float* gAf = (const float*)Ap + (size_t)(m0 + afr) * K + ah;
    const int afs = SWZ(afr);
    const int afslot0 = (ah >> 3) ^ afs;
    const int afslot1 = ((ah >> 3) | 1) ^ afs;

    int aoff[4], boff[4];
#pragma unroll
    for (int i = 0; i < 4; ++i) {
        const int ra = (wv >> 1) * 64 + i * 16 + l15;
        aoff[i] = ra * 32 + ((quad ^ SWZ(ra)) << 3);
        const int rb = (wv & 1) * 64 + i * 16 + l15;
        boff[i] = rb * 32 + ((quad ^ SWZ(rb)) << 3);
    }

    f32x4 acc[4][4] = {};
    for (int kk = 0; kk < K; kk += 32) {
        __syncthreads();                      // previous frag reads done
        if (A_F32) {
            const float* p = gAf + kk;
            float4 f0 = *(const float4*)(p);
            float4 f1 = *(const float4*)(p + 4);
            float4 f2 = *(const float4*)(p + 8);
            float4 f3 = *(const float4*)(p + 12);
            uint4 u0 = { pack2(f0.x, f0.y), pack2(f0.z, f0.w),
                         pack2(f1.x, f1.y), pack2(f1.z, f1.w) };
            uint4 u1 = { pack2(f2.x, f2.y), pack2(f2.z, f2.w),
                         pack2(f3.x, f3.y), pack2(f3.z, f3.w) };
            *(uint4*)(As + afr * 32 + afslot0 * 8) = u0;
            *(uint4*)(As + afr * 32 + afslot1 * 8) = u1;
        } else {
            gl16(gA0 + kk, lA);
            gl16(gA1 + kk, lA + 512);
        }
        gl16(gB0 + kk, lB);
        gl16(gB1 + kk, lB + 512);
        __syncthreads();                      // compiler drains vmcnt+lgkm here

        bf16x8 a[4], b[4];
#pragma unroll
        for (int i = 0; i < 4; ++i) a[i] = ld8(As + aoff[i]);
#pragma unroll
        for (int i = 0; i < 4; ++i) b[i] = ld8(Bs + boff[i]);
#pragma unroll
        for (int i = 0; i < 4; ++i)
#pragma unroll
            for (int j = 0; j < 4; ++j)
                acc[i][j] = __builtin_amdgcn_mfma_f32_16x16x32_bf16(a[i], b[j], acc[i][j], 0, 0, 0);
    }

#pragma unroll
    for (int j = 0; j < 4; ++j) {
        const int col = n0 + (wv & 1) * 64 + j * 16 + l15;
        const float bvv = bias[col];
#pragma unroll
        for (int i = 0; i < 4; ++i) {
            const int rowb = m0 + (wv >> 1) * 64 + i * 16 + quad * 4;
#pragma unroll
            for (int r = 0; r < 4; ++r) {
                const float v = acc[i][j][r] + bvv;
                const int row = rowb + r;
                if (OUT == 1)
                    ((float*)Cp)[(size_t)row * N + col] = v;
                else if (OUT == 0)
                    ((unsigned short*)Cp)[(size_t)row * N + col] = f2bf(v);
                else
                    ((unsigned short*)Cp)[((size_t)(row >> 11) * DM + col) * LL
                                          + (row & (LL - 1))] = f2bf(v);
            }
        }
    }
}

// ---------------------------------------------------------------------------
// Causal attention, fixed-shift softmax. Block = 256 thr, two 64-row q-tiles
// (pair j, 31-j), 64-key chunks. Grid (16, NH, B).
// ---------------------------------------------------------------------------
__global__ __launch_bounds__(256)
void attn2_k(const unsigned short* __restrict__ Qp,
             const unsigned short* __restrict__ Kp,
             const unsigned short* __restrict__ VpT,
             unsigned short* __restrict__ Op) {
    __shared__ unsigned short Ks[64 * 64];      // [key][dk], chunk-swizzled
    __shared__ unsigned short Vs[64 * 64];      // [d][key],  chunk-swizzled
    __shared__ unsigned short Ps[4][16][72];    // per-wave P transpose (+pad)

    const int t = threadIdx.x, lane = t & 63, wv = t >> 6;
    const int quad = lane >> 4, l15 = lane & 15;
    const int h = blockIdx.y, b = blockIdx.z;
    const int pair = blockIdx.x;

    const int srow = wv * 16 + (lane >> 3);
    const int g8 = (lane & 7) ^ ((lane >> 3) & 7);
    unsigned short* lK = Ks + wv * 1024;
    unsigned short* lV = Vs + wv * 1024;
    const int sw = l15 & 7;

    for (int tsel = 0; tsel < 2; ++tsel) {
        const int tile = tsel ? (31 - pair) : pair;
        const int q0 = tile * 64;

        const unsigned short* qp = Qp + (size_t)(b * LL + q0 + wv * 16 + l15) * DM + h * DK;
        const bf16x8 aq0 = ld8(qp + quad * 8);
        const bf16x8 aq1 = ld8(qp + 32 + quad * 8);

        f32x4 acc[4] = {};
        float lrow[4] = {0.f, 0.f, 0.f, 0.f};
        const int rowq = q0 + wv * 16 + quad * 4;

        for (int c = 0; c <= tile; ++c) {
            const int kt = c * 64;
            const unsigned short* kg = Kp + (size_t)(b * LL + kt + srow) * DM + h * DK + g8 * 8;
            const unsigned short* vg = VpT + ((size_t)(b * NH + h) * DK + srow) * LL + kt + g8 * 8;
            __syncthreads();                    // prev chunk's K/V reads done
            gl16(kg, lK);             gl16(kg + (size_t)8 * DM, lK + 512);
            gl16(vg, lV);             gl16(vg + (size_t)8 * LL, lV + 512);
            __syncthreads();

            f32x4 s[4];
#pragma unroll
            for (int sub = 0; sub < 4; ++sub) {
                const int base = (sub * 16 + l15) * 64;
                f32x4 ss = {};
                bf16x8 b0 = ld8(Ks + base + ((quad ^ sw) << 3));
                ss = __builtin_amdgcn_mfma_f32_16x16x32_bf16(aq0, b0, ss, 0, 0, 0);
                bf16x8 b1 = ld8(Ks + base + (((4 + quad) ^ sw) << 3));
                ss = __builtin_amdgcn_mfma_f32_16x16x32_bf16(aq1, b1, ss, 0, 0, 0);
                s[sub] = ss;
            }

            const bool diag = (c == tile);
#pragma unroll
            for (int sub = 0; sub < 4; ++sub) {
                const int col = kt + sub * 16 + l15;
#pragma unroll
                for (int r = 0; r < 4; ++r) {
                    float e = exp2f(fmaf(s[sub][r], 0.18033688011112042f, -16.0f));
                    if (diag && col > rowq + r) e = 0.f;
                    lrow[r] += e;
                    Ps[wv][quad * 4 + r][sub * 16 + l15] = f2bf(e);
                }
            }

#pragma unroll
            for (int ks = 0; ks < 2; ++ks) {
                bf16x8 ap = ld8(&Ps[wv][l15][ks * 32 + quad * 8]);
#pragma unroll
                for (int sub = 0; sub < 4; ++sub) {
                    bf16x8 bv = ld8(Vs + (sub * 16 + l15) * 64 + (((ks * 4 + quad) ^ sw) << 3));
                    acc[sub] = __builtin_amdgcn_mfma_f32_16x16x32_bf16(ap, bv, acc[sub], 0, 0, 0);
                }
            }
        }

#pragma unroll
        for (int r = 0; r < 4; ++r) {
#pragma unroll
            for (int off = 1; off < 16; off <<= 1)
                lrow[r] += __shfl_xor(lrow[r], off, 64);
            lrow[r] = __builtin_amdgcn_rcpf(lrow[r]);
        }
#pragma unroll
        for (int sub = 0; sub < 4; ++sub)
#pragma unroll
            for (int r = 0; r < 4; ++r)
                Op[(size_t)(b * LL + rowq + r) * DM + h * DK + sub * 16 + l15] =
                    f2bf(acc[sub][r] * lrow[r]);
    }
}

// ---------------------------------------------------------------------------
extern "C" void kernel_launch(void* const* d_in, const int* in_sizes, int n_in,
                              void* d_out, int out_size, void* d_ws, size_t ws_size,
                              hipStream_t stream) {
    const float* queries = (const float*)d_in[0];
    const float* keys    = (const float*)d_in[1];
    const float* Wq = (const float*)d_in[3];  const float* bq = (const float*)d_in[4];
    const float* Wd = (const float*)d_in[5];  const float* bd = (const float*)d_in[6];
    const float* Wk = (const float*)d_in[7];  const float* bk = (const float*)d_in[8];
    const float* Wv = (const float*)d_in[9];  const float* bv = (const float*)d_in[10];
    const float* Wo = (const float*)d_in[11]; const float* bo = (const float*)d_in[12];

    char* ws = (char*)d_ws;
    unsigned short* Qp   = (unsigned short*)(ws);
    unsigned short* Kp   = (unsigned short*)(ws + (size_t)8  * 1048576);
    unsigned short* VpT  = (unsigned short*)(ws + (size_t)16 * 1048576);
    unsigned short* Attn = (unsigned short*)(ws + (size_t)24 * 1048576);
    unsigned short* WqT  = Attn;                                              // 2 MB
    unsigned short* WdT  = (unsigned short*)(ws + (size_t)26 * 1048576);      // 0.5 MB
    unsigned short* WkT  = (unsigned short*)(ws + (size_t)26 * 1048576 + 524288);
    unsigned short* WvT  = (unsigned short*)(ws + (size_t)27 * 1048576);
    unsigned short* Lat  = (unsigned short*)(ws + (size_t)27 * 1048576 + 524288); // 2 MB
    unsigned short* WoT  = (unsigned short*)(ws + (size_t)32 * 1048576);      // 2 MB

    wtrans_k<<<dim3(32, 32), 256, 0, stream>>>(Wq, WqT, 1024, 1024);
    wtrans_k<<<dim3(32, 8),  256, 0, stream>>>(Wd, WdT, 1024, 256);
    wtrans_k<<<dim3(8, 32),  256, 0, stream>>>(Wk, WkT, 256, 1024);
    wtrans_k<<<dim3(8, 32),  256, 0, stream>>>(Wv, WvT, 256, 1024);
    wtrans_k<<<dim3(32, 32), 256, 0, stream>>>(Wo, WoT, 1024, 1024);

    gemm128_k<1, 0><<<dim3(8, 32), 256, 0, stream>>>(queries, WqT, bq, Qp,  1024, 1024);
    gemm128_k<1, 0><<<dim3(2, 32), 256, 0, stream>>>(keys,    WdT, bd, Lat, 1024, 256);
    gemm128_k<0, 0><<<dim3(8, 32), 256, 0, stream>>>(Lat,     WkT, bk, Kp,  256,  1024);
    gemm128_k<0, 2><<<dim3(8, 32), 256, 0, stream>>>(Lat,     WvT, bv, VpT, 256,  1024);
    attn2_k<<<dim3(16, NH, 2), 256, 0, stream>>>(Qp, Kp, VpT, Attn);
    gemm128_k<0, 1><<<dim3(8, 32), 256, 0, stream>>>(Attn,    WoT, bo, d_out, 1024, 1024);
}

// Round 3
// 258.734 us; speedup vs baseline: 1.4935x; 1.1915x over previous
//
#include <hip/hip_runtime.h>
#include <stdint.h>

// ---------------------------------------------------------------------------
// DS_MultiHeadLatentAttention, round 3.
// Changes vs round 2 (theory: occupancy, not per-wave efficiency, was the cap):
//  - gemm_k: 128x64 tile, BK=64, attn-style staging (row=128B, 8-slot XOR
//    swizzle -- empirically conflict-free per round-2 SQ_LDS_BANK_CONFLICT).
//    Q/O GEMMs: 512 blocks (2/CU). Fused K+V GEMM (A=Lat shared, N=2048
//    concatenated weights): 1024 blocks (4/CU).
//  - attn3_k: grid (32,16,2) = 1024 blocks (4/CU), one 64-row q-tile each;
//    P stored with truncating bf16 pack (1 op).
//  - prep_k: one kernel does all 5 weight transposes (fp32->bf16 [N][K]) and
//    queries/keys fp32->bf16 conversion; kills the A_F32 GEMM path.
// Dispatches: prep, gemmQ, gemmLat, gemmKV, attn, gemmO  (6 total, was 12).
// Workspace (34 MB, time-phased aliasing):
//   [0,8M)     Qp   (G1 -> attn)
//   [8,16M)    Kb   (prep -> G2), then Kp (G3 -> attn)
//   [16,24M)   Qb   (prep -> G1), then VpT (G3 -> attn)
//   [24,32M)   WqT 2M | Lat 2M | WdT .5M | WkvT 1M  (all dead by G3 end),
//              then Attn (attn -> G5)
//   [32,34M)   WoT  (prep -> G5)
// ---------------------------------------------------------------------------

#define DM 1024
#define NH 16
#define DK 64
#define LL 2048

typedef float  f32x4  __attribute__((ext_vector_type(4)));
typedef __bf16 bf16x8 __attribute__((ext_vector_type(8)));
typedef short  s16x8  __attribute__((ext_vector_type(8)));

__device__ __forceinline__ unsigned short f2bf(float f) {
    union { float f; unsigned int u; } v; v.f = f;
    return (unsigned short)((v.u + 0x7fffu + ((v.u >> 16) & 1u)) >> 16);
}
__device__ __forceinline__ unsigned int pack2(float a, float b) {
    return (unsigned int)f2bf(a) | ((unsigned int)f2bf(b) << 16);
}
__device__ __forceinline__ bf16x8 ld8(const unsigned short* p) {
    s16x8 s = *(const s16x8*)p;
    return __builtin_bit_cast(bf16x8, s);
}
__device__ __forceinline__ void gl16(const void* g, void* l) {
    __builtin_amdgcn_global_load_lds((__attribute__((address_space(1))) void*)(g),
                                     (__attribute__((address_space(3))) void*)(l),
                                     16, 0, 0);
}

// ---------------------------------------------------------------------------
// prep: all weight transposes (fp32 [K][N] -> bf16 [N][K]) + activation
// convert (fp32 -> bf16). Task selected by flat blockIdx.x; branches are
// block-uniform. Grid = 1024+256+256+256+1024+1024+1024 = 4864.
// ---------------------------------------------------------------------------
__global__ __launch_bounds__(256)
void prep_k(const float* __restrict__ Wq, const float* __restrict__ Wd,
            const float* __restrict__ Wk, const float* __restrict__ Wv,
            const float* __restrict__ Wo, const float* __restrict__ queries,
            const float* __restrict__ keys,
            unsigned short* __restrict__ WqT, unsigned short* __restrict__ WdT,
            unsigned short* __restrict__ WkvT, unsigned short* __restrict__ WoT,
            unsigned short* __restrict__ Qb, unsigned short* __restrict__ Kb) {
    int bid = blockIdx.x;
    const int t = threadIdx.x;

    const float* W; unsigned short* WT; int TK, TN;
    if (bid < 1024)      { W = Wq; WT = WqT;  TK = 1024; TN = 1024; }
    else if (bid < 1280) { bid -= 1024; W = Wd; WT = WdT; TK = 1024; TN = 256; }
    else if (bid < 1536) { bid -= 1280; W = Wk; WT = WkvT; TK = 256; TN = 1024; }
    else if (bid < 1792) { bid -= 1536; W = Wv; WT = WkvT + (size_t)1024 * 256; TK = 256; TN = 1024; }
    else if (bid < 2816) { bid -= 1792; W = Wo; WT = WoT;  TK = 1024; TN = 1024; }
    else {
        bid -= 2816;
        const float* src; unsigned short* dst;
        if (bid < 1024) { src = queries; dst = Qb; }
        else            { bid -= 1024; src = keys; dst = Kb; }
        const size_t base = (size_t)bid * 4096;
#pragma unroll
        for (int i = 0; i < 4; ++i) {
            float4 f = *(const float4*)(src + base + (size_t)(i * 256 + t) * 4);
            uint2 u = { pack2(f.x, f.y), pack2(f.z, f.w) };
            *(uint2*)(dst + base + (size_t)(i * 256 + t) * 4) = u;
        }
        return;
    }
    __shared__ float tile[32][33];
    const int tx = t & 31, ty = t >> 5;
    const int bx = bid % (TK / 32), by = bid / (TK / 32);
    const int k0 = bx * 32, n0 = by * 32;
#pragma unroll
    for (int i = 0; i < 4; ++i)
        tile[ty + 8 * i][tx] = W[(size_t)(k0 + ty + 8 * i) * TN + n0 + tx];
    __syncthreads();
#pragma unroll
    for (int i = 0; i < 4; ++i)
        WT[(size_t)(n0 + ty + 8 * i) * TK + k0 + tx] = f2bf(tile[tx][ty + 8 * i]);
}

// ---------------------------------------------------------------------------
// GEMM: C[M,N] = A[M,K] @ BT[N,K]^T + bias.  128(M) x 64(N) tile, BK=64.
// 4 waves in 2x2: wave -> 64m x 32n quadrant, 4x2 accs, 16 MFMA/iter.
// LDS rows are 64 shorts (128B); slot swizzle chunk^(row&7) -- identical to
// the round-2 attention staging pattern (measured near-conflict-free).
// OUT: 0 = bf16 row-major, 1 = f32 row-major, 3 = fused K|V (n<1024 -> Kp
// row-major [tok][1024]; n>=1024 -> VpT [b][n-1024][l]).
// ---------------------------------------------------------------------------
template<int OUT>
__global__ __launch_bounds__(256)
void gemm_k(const unsigned short* __restrict__ Ap, const unsigned short* __restrict__ Bt,
            const float* __restrict__ bias, const float* __restrict__ bias2,
            void* __restrict__ Cp, void* __restrict__ Cp2, int K, int N) {
    __shared__ unsigned short As[128 * 64];   // 16 KB
    __shared__ unsigned short Bs[64 * 64];    //  8 KB

    const int t = threadIdx.x, lane = t & 63, wv = t >> 6;
    const int quad = lane >> 4, l15 = lane & 15;
    const int m0 = blockIdx.y * 128, n0 = blockIdx.x * 64;

    // staging: per lane 16B; row = base + (lane>>3), chunk g8 = (lane&7)^(row&7)
    const int lr8 = lane >> 3;
    const int g8 = (lane & 7) ^ (lr8 & 7);
    const unsigned short* gA = Ap + (size_t)(m0 + wv * 32 + lr8) * K + g8 * 8;
    const unsigned short* gB = Bt + (size_t)(n0 + wv * 16 + lr8) * K + g8 * 8;
    unsigned short* lA = As + wv * 2048;      // 32 rows/wave, 4 sweeps of 8
    unsigned short* lB = Bs + wv * 1024;      // 16 rows/wave, 2 sweeps of 8

    int aoff[4][2], boff[2][2];
#pragma unroll
    for (int i = 0; i < 4; ++i) {
        const int ra = (wv >> 1) * 64 + i * 16 + l15;
#pragma unroll
        for (int ks = 0; ks < 2; ++ks)
            aoff[i][ks] = ra * 64 + (((ks * 4 + quad) ^ (ra & 7)) << 3);
    }
#pragma unroll
    for (int j = 0; j < 2; ++j) {
        const int rb = (wv & 1) * 32 + j * 16 + l15;
#pragma unroll
        for (int ks = 0; ks < 2; ++ks)
            boff[j][ks] = rb * 64 + (((ks * 4 + quad) ^ (rb & 7)) << 3);
    }

    f32x4 acc[4][2] = {};
    for (int kk = 0; kk < K; kk += 64) {
        __syncthreads();
#pragma unroll
        for (int s = 0; s < 4; ++s)
            gl16(gA + kk + (size_t)s * 8 * K, lA + s * 512);
#pragma unroll
        for (int s = 0; s < 2; ++s)
            gl16(gB + kk + (size_t)s * 8 * K, lB + s * 512);
        __syncthreads();

#pragma unroll
        for (int ks = 0; ks < 2; ++ks) {
            bf16x8 a[4], b[2];
#pragma unroll
            for (int i = 0; i < 4; ++i) a[i] = ld8(As + aoff[i][ks]);
#pragma unroll
            for (int j = 0; j < 2; ++j) b[j] = ld8(Bs + boff[j][ks]);
#pragma unroll
            for (int i = 0; i < 4; ++i)
#pragma unroll
                for (int j = 0; j < 2; ++j)
                    acc[i][j] = __builtin_amdgcn_mfma_f32_16x16x32_bf16(a[i], b[j], acc[i][j], 0, 0, 0);
        }
    }

    const bool isV = (OUT == 3) && (n0 >= 1024);
#pragma unroll
    for (int j = 0; j < 2; ++j) {
        const int col = n0 + (wv & 1) * 32 + j * 16 + l15;
        const float bvv = isV ? bias2[col - 1024] : bias[col];
#pragma unroll
        for (int i = 0; i < 4; ++i) {
            const int rowb = m0 + (wv >> 1) * 64 + i * 16 + quad * 4;
#pragma unroll
            for (int r = 0; r < 4; ++r) {
                const float v = acc[i][j][r] + bvv;
                const int row = rowb + r;
                if (OUT == 1)
                    ((float*)Cp)[(size_t)row * N + col] = v;
                else if (OUT == 0)
                    ((unsigned short*)Cp)[(size_t)row * N + col] = f2bf(v);
                else if (!isV)
                    ((unsigned short*)Cp)[(size_t)row * 1024 + col] = f2bf(v);
                else
                    ((unsigned short*)Cp2)[((size_t)(row >> 11) * 1024 + (col - 1024)) * LL
                                           + (row & (LL - 1))] = f2bf(v);
            }
        }
    }
}

// ---------------------------------------------------------------------------
// Causal attention, fixed-shift softmax. Block = 256 thr, one 64-row q-tile,
// 64-key chunks. Grid (32, NH, B) = 1024 blocks.
// ---------------------------------------------------------------------------
__global__ __launch_bounds__(256)
void attn3_k(const unsigned short* __restrict__ Qp,
             const unsigned short* __restrict__ Kp,
             const unsigned short* __restrict__ VpT,
             unsigned short* __restrict__ Op) {
    __shared__ unsigned short Ks[64 * 64];
    __shared__ unsigned short Vs[64 * 64];
    __shared__ unsigned short Ps[4][16][72];

    const int t = threadIdx.x, lane = t & 63, wv = t >> 6;
    const int quad = lane >> 4, l15 = lane & 15;
    const int tile = blockIdx.x, h = blockIdx.y, b = blockIdx.z;
    const int q0 = tile * 64;

    const int srow = wv * 16 + (lane >> 3);
    const int g8 = (lane & 7) ^ ((lane >> 3) & 7);
    unsigned short* lK = Ks + wv * 1024;
    unsigned short* lV = Vs + wv * 1024;
    const int sw = l15 & 7;

    const unsigned short* qp = Qp + (size_t)(b * LL + q0 + wv * 16 + l15) * DM + h * DK;
    const bf16x8 aq0 = ld8(qp + quad * 8);
    const bf16x8 aq1 = ld8(qp + 32 + quad * 8);

    f32x4 acc[4] = {};
    float lrow[4] = {0.f, 0.f, 0.f, 0.f};
    const int rowq = q0 + wv * 16 + quad * 4;

    for (int c = 0; c <= tile; ++c) {
        const int kt = c * 64;
        const unsigned short* kg = Kp + (size_t)(b * LL + kt + srow) * DM + h * DK + g8 * 8;
        const unsigned short* vg = VpT + ((size_t)(b * NH + h) * DK + srow) * LL + kt + g8 * 8;
        __syncthreads();
        gl16(kg, lK);             gl16(kg + (size_t)8 * DM, lK + 512);
        gl16(vg, lV);             gl16(vg + (size_t)8 * LL, lV + 512);
        __syncthreads();

        f32x4 s[4];
#pragma unroll
        for (int sub = 0; sub < 4; ++sub) {
            const int base = (sub * 16 + l15) * 64;
            f32x4 ss = {};
            bf16x8 b0 = ld8(Ks + base + ((quad ^ sw) << 3));
            ss = __builtin_amdgcn_mfma_f32_16x16x32_bf16(aq0, b0, ss, 0, 0, 0);
            bf16x8 b1 = ld8(Ks + base + (((4 + quad) ^ sw) << 3));
            ss = __builtin_amdgcn_mfma_f32_16x16x32_bf16(aq1, b1, ss, 0, 0, 0);
            s[sub] = ss;
        }

        const bool diag = (c == tile);
#pragma unroll
        for (int sub = 0; sub < 4; ++sub) {
            const int col = kt + sub * 16 + l15;
#pragma unroll
            for (int r = 0; r < 4; ++r) {
                float e = exp2f(fmaf(s[sub][r], 0.18033688011112042f, -16.0f));
                if (diag && col > rowq + r) e = 0.f;
                lrow[r] += e;
                // truncating bf16 pack (P in [0, 2^-10]; trunc error cancels in ratio)
                Ps[wv][quad * 4 + r][sub * 16 + l15] =
                    (unsigned short)(__builtin_bit_cast(unsigned int, e) >> 16);
            }
        }

#pragma unroll
        for (int ks = 0; ks < 2; ++ks) {
            bf16x8 ap = ld8(&Ps[wv][l15][ks * 32 + quad * 8]);
#pragma unroll
            for (int sub = 0; sub < 4; ++sub) {
                bf16x8 bv = ld8(Vs + (sub * 16 + l15) * 64 + (((ks * 4 + quad) ^ sw) << 3));
                acc[sub] = __builtin_amdgcn_mfma_f32_16x16x32_bf16(ap, bv, acc[sub], 0, 0, 0);
            }
        }
    }

#pragma unroll
    for (int r = 0; r < 4; ++r) {
#pragma unroll
        for (int off = 1; off < 16; off <<= 1)
            lrow[r] += __shfl_xor(lrow[r], off, 64);
        lrow[r] = __builtin_amdgcn_rcpf(lrow[r]);
    }
#pragma unroll
    for (int sub = 0; sub < 4; ++sub)
#pragma unroll
        for (int r = 0; r < 4; ++r)
            Op[(size_t)(b * LL + rowq + r) * DM + h * DK + sub * 16 + l15] =
                f2bf(acc[sub][r] * lrow[r]);
}

// ---------------------------------------------------------------------------
extern "C" void kernel_launch(void* const* d_in, const int* in_sizes, int n_in,
                              void* d_out, int out_size, void* d_ws, size_t ws_size,
                              hipStream_t stream) {
    const float* queries = (const float*)d_in[0];
    const float* keys    = (const float*)d_in[1];
    const float* Wq = (const float*)d_in[3];  const float* bq = (const float*)d_in[4];
    const float* Wd = (const float*)d_in[5];  const float* bd = (const float*)d_in[6];
    const float* Wk = (const float*)d_in[7];  const float* bk = (const float*)d_in[8];
    const float* Wv = (const float*)d_in[9];  const float* bv = (const float*)d_in[10];
    const float* Wo = (const float*)d_in[11]; const float* bo = (const float*)d_in[12];

    char* ws = (char*)d_ws;
    const size_t MB = 1048576;
    unsigned short* Qp   = (unsigned short*)(ws);                   // [0,8M)
    unsigned short* Kb   = (unsigned short*)(ws + 8 * MB);          // prep->G2
    unsigned short* Kp   = (unsigned short*)(ws + 8 * MB);          // G3->attn
    unsigned short* Qb   = (unsigned short*)(ws + 16 * MB);         // prep->G1
    unsigned short* VpT  = (unsigned short*)(ws + 16 * MB);         // G3->attn
    unsigned short* WqT  = (unsigned short*)(ws + 24 * MB);         // prep->G1
    unsigned short* Lat  = (unsigned short*)(ws + 26 * MB);         // G2->G3
    unsigned short* WdT  = (unsigned short*)(ws + 28 * MB);         // prep->G2
    unsigned short* WkvT = (unsigned short*)(ws + 28 * MB + 524288);// prep->G3
    unsigned short* Attn = (unsigned short*)(ws + 24 * MB);         // attn->G5
    unsigned short* WoT  = (unsigned short*)(ws + 32 * MB);         // prep->G5

    prep_k<<<4864, 256, 0, stream>>>(Wq, Wd, Wk, Wv, Wo, queries, keys,
                                     WqT, WdT, WkvT, WoT, Qb, Kb);
    gemm_k<0><<<dim3(16, 32), 256, 0, stream>>>(Qb,  WqT,  bq, nullptr, Qp,   nullptr, 1024, 1024);
    gemm_k<0><<<dim3(4, 32),  256, 0, stream>>>(Kb,  WdT,  bd, nullptr, Lat,  nullptr, 1024, 256);
    gemm_k<3><<<dim3(32, 32), 256, 0, stream>>>(Lat, WkvT, bk, bv,      Kp,   VpT,     256,  2048);
    attn3_k<<<dim3(32, NH, 2), 256, 0, stream>>>(Qp, Kp, VpT, Attn);
    gemm_k<1><<<dim3(16, 32), 256, 0, stream>>>(Attn, WoT, bo, nullptr, d_out, nullptr, 1024, 1024);
}

// Round 4
// 227.672 us; speedup vs baseline: 1.6972x; 1.1364x over previous
//
#include <hip/hip_runtime.h>
#include <stdint.h>

// ---------------------------------------------------------------------------
// DS_MultiHeadLatentAttention, round 4.
// Changes vs round 3:
//  - attn4_k: 512-thread blocks (8 waves = 2 groups of 4), paired q-tiles
//    (j, 31-j) for uniform work, even/odd key-chunk split across the two
//    groups (fixed-shift softmax partials are additive -> trivial combine
//    through LDS once per tile). Sequential depth 33 -> 17 iterations,
//    resident waves/CU 8 -> 16. Grid (16,16,2)=512.
//  - gemm64_k: 64x64 tile BK=64 for all GEMMs -> grids 1024-2048 (4-8
//    blocks/CU) so barrier drains overlap across co-resident blocks.
//    Q-proj + Lat-proj fused into one 1280-block dispatch.
// Dispatches: prep, gemmQLat, gemmKV, attn, gemmO (5).
// Workspace (34 MB, time-phased):
//   [0,8M)   Qp      [8,16M)  Kb -> Kp      [16,24M) Qb -> VpT
//   [24,32M) WqT(2M)|Lat(2M)|WdT(.5M)|WkvT(1M) -> Attn
//   [32,34M) WoT
// ---------------------------------------------------------------------------

#define DM 1024
#define NH 16
#define DK 64
#define LL 2048

typedef float  f32x4  __attribute__((ext_vector_type(4)));
typedef __bf16 bf16x8 __attribute__((ext_vector_type(8)));
typedef short  s16x8  __attribute__((ext_vector_type(8)));

__device__ __forceinline__ unsigned short f2bf(float f) {
    union { float f; unsigned int u; } v; v.f = f;
    return (unsigned short)((v.u + 0x7fffu + ((v.u >> 16) & 1u)) >> 16);
}
__device__ __forceinline__ unsigned int pack2(float a, float b) {
    return (unsigned int)f2bf(a) | ((unsigned int)f2bf(b) << 16);
}
__device__ __forceinline__ bf16x8 ld8(const unsigned short* p) {
    s16x8 s = *(const s16x8*)p;
    return __builtin_bit_cast(bf16x8, s);
}
__device__ __forceinline__ void gl16(const void* g, void* l) {
    __builtin_amdgcn_global_load_lds((__attribute__((address_space(1))) void*)(g),
                                     (__attribute__((address_space(3))) void*)(l),
                                     16, 0, 0);
}

// ---------------------------------------------------------------------------
// prep: 5 weight transposes (fp32 [K][N] -> bf16 [N][K]) + queries/keys
// fp32 -> bf16. Grid = 1024+256+256+256+1024+1024+1024 = 4864.
// ---------------------------------------------------------------------------
__global__ __launch_bounds__(256)
void prep_k(const float* __restrict__ Wq, const float* __restrict__ Wd,
            const float* __restrict__ Wk, const float* __restrict__ Wv,
            const float* __restrict__ Wo, const float* __restrict__ queries,
            const float* __restrict__ keys,
            unsigned short* __restrict__ WqT, unsigned short* __restrict__ WdT,
            unsigned short* __restrict__ WkvT, unsigned short* __restrict__ WoT,
            unsigned short* __restrict__ Qb, unsigned short* __restrict__ Kb) {
    int bid = blockIdx.x;
    const int t = threadIdx.x;

    const float* W; unsigned short* WT; int TK, TN;
    if (bid < 1024)      { W = Wq; WT = WqT;  TK = 1024; TN = 1024; }
    else if (bid < 1280) { bid -= 1024; W = Wd; WT = WdT; TK = 1024; TN = 256; }
    else if (bid < 1536) { bid -= 1280; W = Wk; WT = WkvT; TK = 256; TN = 1024; }
    else if (bid < 1792) { bid -= 1536; W = Wv; WT = WkvT + (size_t)1024 * 256; TK = 256; TN = 1024; }
    else if (bid < 2816) { bid -= 1792; W = Wo; WT = WoT;  TK = 1024; TN = 1024; }
    else {
        bid -= 2816;
        const float* src; unsigned short* dst;
        if (bid < 1024) { src = queries; dst = Qb; }
        else            { bid -= 1024; src = keys; dst = Kb; }
        const size_t base = (size_t)bid * 4096;
#pragma unroll
        for (int i = 0; i < 4; ++i) {
            float4 f = *(const float4*)(src + base + (size_t)(i * 256 + t) * 4);
            uint2 u = { pack2(f.x, f.y), pack2(f.z, f.w) };
            *(uint2*)(dst + base + (size_t)(i * 256 + t) * 4) = u;
        }
        return;
    }
    __shared__ float tile[32][33];
    const int tx = t & 31, ty = t >> 5;
    const int bx = bid % (TK / 32), by = bid / (TK / 32);
    const int k0 = bx * 32, n0 = by * 32;
#pragma unroll
    for (int i = 0; i < 4; ++i)
        tile[ty + 8 * i][tx] = W[(size_t)(k0 + ty + 8 * i) * TN + n0 + tx];
    __syncthreads();
#pragma unroll
    for (int i = 0; i < 4; ++i)
        WT[(size_t)(n0 + ty + 8 * i) * TK + k0 + tx] = f2bf(tile[tx][ty + 8 * i]);
}

// ---------------------------------------------------------------------------
// GEMM 64x64 tile, BK=64, 4 waves (2x2 quadrants, 2x2 accs, 8 MFMA/iter).
// MODE 1: C = A@Bt+bias, f32 out, N=1024 (O-proj), grid 1024.
// MODE 2: fused Q+Lat. bid<1024: Qb@WqT+bq -> Qp bf16 (N=1024);
//         bid>=1024: Kb@WdT+bd -> Lat bf16 (N=256). grid 1280. K=1024.
// MODE 3: fused K|V: Lat@WkvT, N=2048, K=256. col<1024 -> Kp row-major
//         +bias; col>=1024 -> VpT [b][col-1024][l] +bias2. grid 2048.
// ---------------------------------------------------------------------------
template<int MODE>
__global__ __launch_bounds__(256)
void gemm64_k(const unsigned short* __restrict__ Ap, const unsigned short* __restrict__ Bt,
              const float* __restrict__ bias, void* __restrict__ Cp,
              const unsigned short* __restrict__ Ap2, const unsigned short* __restrict__ Bt2,
              const float* __restrict__ bias2, void* __restrict__ Cp2,
              int K) {
    __shared__ unsigned short As[64 * 64];   // 8 KB
    __shared__ unsigned short Bs[64 * 64];   // 8 KB

    int bid = blockIdx.x;
    const unsigned short* A = Ap;
    const unsigned short* B = Bt;
    const float* bs = bias;
    bool second = false;
    int lognb = (MODE == 3) ? 5 : 4;
    if (MODE == 2 && bid >= 1024) {
        bid -= 1024; A = Ap2; B = Bt2; bs = bias2; second = true; lognb = 2;
    }
    const int n0 = (bid & ((1 << lognb) - 1)) * 64;
    const int m0 = (bid >> lognb) * 64;

    const int t = threadIdx.x, lane = t & 63, wv = t >> 6;
    const int quad = lane >> 4, l15 = lane & 15;

    const int lr8 = lane >> 3;
    const int g8 = (lane & 7) ^ (lr8 & 7);
    const unsigned short* gA = A + (size_t)(m0 + wv * 16 + lr8) * K + g8 * 8;
    const unsigned short* gB = B + (size_t)(n0 + wv * 16 + lr8) * K + g8 * 8;
    unsigned short* lA = As + wv * 1024;
    unsigned short* lB = Bs + wv * 1024;

    int aoff[2][2], boff[2][2];
#pragma unroll
    for (int i = 0; i < 2; ++i) {
        const int ra = (wv >> 1) * 32 + i * 16 + l15;
        const int rb = (wv & 1) * 32 + i * 16 + l15;
#pragma unroll
        for (int ks = 0; ks < 2; ++ks) {
            aoff[i][ks] = ra * 64 + (((ks * 4 + quad) ^ (ra & 7)) << 3);
            boff[i][ks] = rb * 64 + (((ks * 4 + quad) ^ (rb & 7)) << 3);
        }
    }

    f32x4 acc[2][2] = {};
    for (int kk = 0; kk < K; kk += 64) {
        __syncthreads();
        gl16(gA + kk, lA);               gl16(gA + kk + (size_t)8 * K, lA + 512);
        gl16(gB + kk, lB);               gl16(gB + kk + (size_t)8 * K, lB + 512);
        __syncthreads();
#pragma unroll
        for (int ks = 0; ks < 2; ++ks) {
            bf16x8 a[2], b[2];
#pragma unroll
            for (int i = 0; i < 2; ++i) a[i] = ld8(As + aoff[i][ks]);
#pragma unroll
            for (int j = 0; j < 2; ++j) b[j] = ld8(Bs + boff[j][ks]);
#pragma unroll
            for (int i = 0; i < 2; ++i)
#pragma unroll
                for (int j = 0; j < 2; ++j)
                    acc[i][j] = __builtin_amdgcn_mfma_f32_16x16x32_bf16(a[i], b[j], acc[i][j], 0, 0, 0);
        }
    }

#pragma unroll
    for (int j = 0; j < 2; ++j) {
        const int col = n0 + (wv & 1) * 32 + j * 16 + l15;
        const bool isV = (MODE == 3) && (col >= 1024);
        const float bvv = isV ? bias2[col - 1024] : bs[col];
#pragma unroll
        for (int i = 0; i < 2; ++i) {
            const int rowb = m0 + (wv >> 1) * 32 + i * 16 + quad * 4;
#pragma unroll
            for (int r = 0; r < 4; ++r) {
                const float v = acc[i][j][r] + bvv;
                const int row = rowb + r;
                if (MODE == 1)
                    ((float*)Cp)[(size_t)row * 1024 + col] = v;
                else if (MODE == 2) {
                    if (second) ((unsigned short*)Cp2)[(size_t)row * 256 + col] = f2bf(v);
                    else        ((unsigned short*)Cp)[(size_t)row * 1024 + col] = f2bf(v);
                } else {  // MODE 3
                    if (!isV)   ((unsigned short*)Cp)[(size_t)row * 1024 + col] = f2bf(v);
                    else        ((unsigned short*)Cp2)[((size_t)(row >> 11) * 1024 + (col - 1024)) * LL
                                                       + (row & (LL - 1))] = f2bf(v);
                }
            }
        }
    }
}

// ---------------------------------------------------------------------------
// Causal attention: 512 thr (2 groups of 4 waves), paired q-tiles (j, 31-j),
// even/odd 64-key chunk split across groups, fixed-shift softmax (additive
// partials), LDS combine per tile. Grid (16, NH, B) = 512.
// ---------------------------------------------------------------------------
__global__ __launch_bounds__(512)
void attn4_k(const unsigned short* __restrict__ Qp,
             const unsigned short* __restrict__ Kp,
             const unsigned short* __restrict__ VpT,
             unsigned short* __restrict__ Op) {
    __shared__ unsigned short Ks[2][4096];      // 16 KB  (also combine buffer)
    __shared__ unsigned short Vs[2][4096];      // 16 KB
    __shared__ unsigned short Ps[8][16][72];    // 18 KB

    const int t = threadIdx.x, lane = t & 63, wv = t >> 6;
    const int grp = wv >> 2, w4 = wv & 3;
    const int quad = lane >> 4, l15 = lane & 15;
    const int pair = blockIdx.x, h = blockIdx.y, b = blockIdx.z;

    const int srow = w4 * 16 + (lane >> 3);
    const int g8 = (lane & 7) ^ ((lane >> 3) & 7);
    unsigned short* lK = &Ks[grp][w4 * 1024];
    unsigned short* lV = &Vs[grp][w4 * 1024];
    const int sw = l15 & 7;
    float* cb = (float*)&Ks[0][0];              // 20 KB combine area

    for (int tsel = 0; tsel < 2; ++tsel) {
        const int tile = tsel ? (31 - pair) : pair;
        const int q0 = tile * 64;

        const unsigned short* qp = Qp + (size_t)(b * LL + q0 + w4 * 16 + l15) * DM + h * DK;
        const bf16x8 aq0 = ld8(qp + quad * 8);
        const bf16x8 aq1 = ld8(qp + 32 + quad * 8);

        f32x4 acc[4] = {};
        float lrow[4] = {0.f, 0.f, 0.f, 0.f};
        const int rowq = q0 + w4 * 16 + quad * 4;

        const int nit = tile / 2 + 1;
        for (int it = 0; it < nit; ++it) {
            const int c = 2 * it + grp;
            const bool active = (c <= tile);
            const int kt = c * 64;
            __syncthreads();
            if (active) {
                const unsigned short* kg = Kp + (size_t)(b * LL + kt + srow) * DM + h * DK + g8 * 8;
                const unsigned short* vg = VpT + ((size_t)(b * NH + h) * DK + srow) * LL + kt + g8 * 8;
                gl16(kg, lK);             gl16(kg + (size_t)8 * DM, lK + 512);
                gl16(vg, lV);             gl16(vg + (size_t)8 * LL, lV + 512);
            }
            __syncthreads();
            if (!active) continue;

            f32x4 s[4];
#pragma unroll
            for (int sub = 0; sub < 4; ++sub) {
                const int base = (sub * 16 + l15) * 64;
                f32x4 ss = {};
                bf16x8 b0 = ld8(&Ks[grp][base + ((quad ^ sw) << 3)]);
                ss = __builtin_amdgcn_mfma_f32_16x16x32_bf16(aq0, b0, ss, 0, 0, 0);
                bf16x8 b1 = ld8(&Ks[grp][base + (((4 + quad) ^ sw) << 3)]);
                ss = __builtin_amdgcn_mfma_f32_16x16x32_bf16(aq1, b1, ss, 0, 0, 0);
                s[sub] = ss;
            }

            const bool diag = (c == tile);
#pragma unroll
            for (int sub = 0; sub < 4; ++sub) {
                const int col = kt + sub * 16 + l15;
#pragma unroll
                for (int r = 0; r < 4; ++r) {
                    float e = exp2f(fmaf(s[sub][r], 0.18033688011112042f, -16.0f));
                    if (diag && col > rowq + r) e = 0.f;
                    lrow[r] += e;
                    Ps[wv][quad * 4 + r][sub * 16 + l15] =
                        (unsigned short)(__builtin_bit_cast(unsigned int, e) >> 16);
                }
            }

#pragma unroll
            for (int ks = 0; ks < 2; ++ks) {
                bf16x8 ap = ld8(&Ps[wv][l15][ks * 32 + quad * 8]);
#pragma unroll
                for (int sub = 0; sub < 4; ++sub) {
                    bf16x8 bv = ld8(&Vs[grp][(sub * 16 + l15) * 64 + (((ks * 4 + quad) ^ sw) << 3)]);
                    acc[sub] = __builtin_amdgcn_mfma_f32_16x16x32_bf16(ap, bv, acc[sub], 0, 0, 0);
                }
            }
        }

        // combine group 1 -> group 0 through LDS; group 0 finalizes + stores
        __syncthreads();
        const int base = (w4 * 64 + lane) * 20;
        if (grp == 1) {
#pragma unroll
            for (int sub = 0; sub < 4; ++sub)
#pragma unroll
                for (int r = 0; r < 4; ++r) cb[base + sub * 4 + r] = acc[sub][r];
#pragma unroll
            for (int r = 0; r < 4; ++r) cb[base + 16 + r] = lrow[r];
        }
        __syncthreads();
        if (grp == 0) {
#pragma unroll
            for (int sub = 0; sub < 4; ++sub)
#pragma unroll
                for (int r = 0; r < 4; ++r) acc[sub][r] += cb[base + sub * 4 + r];
#pragma unroll
            for (int r = 0; r < 4; ++r) {
                lrow[r] += cb[base + 16 + r];
#pragma unroll
                for (int off = 1; off < 16; off <<= 1)
                    lrow[r] += __shfl_xor(lrow[r], off, 64);
                lrow[r] = __builtin_amdgcn_rcpf(lrow[r]);
            }
#pragma unroll
            for (int sub = 0; sub < 4; ++sub)
#pragma unroll
                for (int r = 0; r < 4; ++r)
                    Op[(size_t)(b * LL + rowq + r) * DM + h * DK + sub * 16 + l15] =
                        f2bf(acc[sub][r] * lrow[r]);
        }
        // next tile's first barrier+staging happens only after group 0 passes
        // its next __syncthreads -> combine reads are safe.
    }
}

// ---------------------------------------------------------------------------
extern "C" void kernel_launch(void* const* d_in, const int* in_sizes, int n_in,
                              void* d_out, int out_size, void* d_ws, size_t ws_size,
                              hipStream_t stream) {
    const float* queries = (const float*)d_in[0];
    const float* keys    = (const float*)d_in[1];
    const float* Wq = (const float*)d_in[3];  const float* bq = (const float*)d_in[4];
    const float* Wd = (const float*)d_in[5];  const float* bd = (const float*)d_in[6];
    const float* Wk = (const float*)d_in[7];  const float* bk = (const float*)d_in[8];
    const float* Wv = (const float*)d_in[9];  const float* bv = (const float*)d_in[10];
    const float* Wo = (const float*)d_in[11]; const float* bo = (const float*)d_in[12];

    char* ws = (char*)d_ws;
    const size_t MB = 1048576;
    unsigned short* Qp   = (unsigned short*)(ws);                   // [0,8M)
    unsigned short* Kb   = (unsigned short*)(ws + 8 * MB);          // prep->QLat
    unsigned short* Kp   = (unsigned short*)(ws + 8 * MB);          // KV->attn
    unsigned short* Qb   = (unsigned short*)(ws + 16 * MB);         // prep->QLat
    unsigned short* VpT  = (unsigned short*)(ws + 16 * MB);         // KV->attn
    unsigned short* WqT  = (unsigned short*)(ws + 24 * MB);         // prep->QLat
    unsigned short* Lat  = (unsigned short*)(ws + 26 * MB);         // QLat->KV
    unsigned short* WdT  = (unsigned short*)(ws + 28 * MB);         // prep->QLat
    unsigned short* WkvT = (unsigned short*)(ws + 28 * MB + 524288);// prep->KV
    unsigned short* Attn = (unsigned short*)(ws + 24 * MB);         // attn->O
    unsigned short* WoT  = (unsigned short*)(ws + 32 * MB);         // prep->O

    prep_k<<<4864, 256, 0, stream>>>(Wq, Wd, Wk, Wv, Wo, queries, keys,
                                     WqT, WdT, WkvT, WoT, Qb, Kb);
    gemm64_k<2><<<1280, 256, 0, stream>>>(Qb, WqT, bq, Qp, Kb, WdT, bd, Lat, 1024);
    gemm64_k<3><<<2048, 256, 0, stream>>>(Lat, WkvT, bk, Kp, nullptr, nullptr, bv, VpT, 256);
    attn4_k<<<dim3(16, NH, 2), 512, 0, stream>>>(Qp, Kp, VpT, Attn);
    gemm64_k<1><<<1024, 256, 0, stream>>>(Attn, WoT, bo, d_out, nullptr, nullptr, nullptr, nullptr, 1024);
}

// Round 5
// 209.421 us; speedup vs baseline: 1.8451x; 1.0871x over previous
//
#include <hip/hip_runtime.h>
#include <stdint.h>

// ---------------------------------------------------------------------------
// DS_MultiHeadLatentAttention, round 5.
// Change vs round 4: XCD-clustered block mappings (assume xcd = bid % 8
// round-robin; perf heuristic only, correctness-independent).
//  - GEMMs: each XCD sweeps all n for an 8-m-block window -> per-XCD L2
//    working set (A-window + full B) fits 4 MB -> A/B fetched ~once.
//  - attn: each XCD owns 4 (h,b) combos (4 x 512 KB K/V) -> K/V L2-resident.
// Kernel bodies identical to round 4 (passing, absmax 0.0195).
// Dispatches: prep, gemmQLat, gemmKV, attn, gemmO (5).
// Workspace (34 MB, time-phased):
//   [0,8M)   Qp      [8,16M)  Kb -> Kp      [16,24M) Qb -> VpT
//   [24,32M) WqT(2M)|Lat(2M)|WdT(.5M)|WkvT(1M) -> Attn
//   [32,34M) WoT
// ---------------------------------------------------------------------------

#define DM 1024
#define NH 16
#define DK 64
#define LL 2048

typedef float  f32x4  __attribute__((ext_vector_type(4)));
typedef __bf16 bf16x8 __attribute__((ext_vector_type(8)));
typedef short  s16x8  __attribute__((ext_vector_type(8)));

__device__ __forceinline__ unsigned short f2bf(float f) {
    union { float f; unsigned int u; } v; v.f = f;
    return (unsigned short)((v.u + 0x7fffu + ((v.u >> 16) & 1u)) >> 16);
}
__device__ __forceinline__ unsigned int pack2(float a, float b) {
    return (unsigned int)f2bf(a) | ((unsigned int)f2bf(b) << 16);
}
__device__ __forceinline__ bf16x8 ld8(const unsigned short* p) {
    s16x8 s = *(const s16x8*)p;
    return __builtin_bit_cast(bf16x8, s);
}
__device__ __forceinline__ void gl16(const void* g, void* l) {
    __builtin_amdgcn_global_load_lds((__attribute__((address_space(1))) void*)(g),
                                     (__attribute__((address_space(3))) void*)(l),
                                     16, 0, 0);
}

// ---------------------------------------------------------------------------
// prep: 5 weight transposes (fp32 [K][N] -> bf16 [N][K]) + queries/keys
// fp32 -> bf16. Grid = 1024+256+256+256+1024+1024+1024 = 4864.
// ---------------------------------------------------------------------------
__global__ __launch_bounds__(256)
void prep_k(const float* __restrict__ Wq, const float* __restrict__ Wd,
            const float* __restrict__ Wk, const float* __restrict__ Wv,
            const float* __restrict__ Wo, const float* __restrict__ queries,
            const float* __restrict__ keys,
            unsigned short* __restrict__ WqT, unsigned short* __restrict__ WdT,
            unsigned short* __restrict__ WkvT, unsigned short* __restrict__ WoT,
            unsigned short* __restrict__ Qb, unsigned short* __restrict__ Kb) {
    int bid = blockIdx.x;
    const int t = threadIdx.x;

    const float* W; unsigned short* WT; int TK, TN;
    if (bid < 1024)      { W = Wq; WT = WqT;  TK = 1024; TN = 1024; }
    else if (bid < 1280) { bid -= 1024; W = Wd; WT = WdT; TK = 1024; TN = 256; }
    else if (bid < 1536) { bid -= 1280; W = Wk; WT = WkvT; TK = 256; TN = 1024; }
    else if (bid < 1792) { bid -= 1536; W = Wv; WT = WkvT + (size_t)1024 * 256; TK = 256; TN = 1024; }
    else if (bid < 2816) { bid -= 1792; W = Wo; WT = WoT;  TK = 1024; TN = 1024; }
    else {
        bid -= 2816;
        const float* src; unsigned short* dst;
        if (bid < 1024) { src = queries; dst = Qb; }
        else            { bid -= 1024; src = keys; dst = Kb; }
        const size_t base = (size_t)bid * 4096;
#pragma unroll
        for (int i = 0; i < 4; ++i) {
            float4 f = *(const float4*)(src + base + (size_t)(i * 256 + t) * 4);
            uint2 u = { pack2(f.x, f.y), pack2(f.z, f.w) };
            *(uint2*)(dst + base + (size_t)(i * 256 + t) * 4) = u;
        }
        return;
    }
    __shared__ float tile[32][33];
    const int tx = t & 31, ty = t >> 5;
    const int bx = bid % (TK / 32), by = bid / (TK / 32);
    const int k0 = bx * 32, n0 = by * 32;
#pragma unroll
    for (int i = 0; i < 4; ++i)
        tile[ty + 8 * i][tx] = W[(size_t)(k0 + ty + 8 * i) * TN + n0 + tx];
    __syncthreads();
#pragma unroll
    for (int i = 0; i < 4; ++i)
        WT[(size_t)(n0 + ty + 8 * i) * TK + k0 + tx] = f2bf(tile[tx][ty + 8 * i]);
}

// ---------------------------------------------------------------------------
// GEMM 64x64 tile, BK=64, 4 waves (2x2 quadrants, 2x2 accs, 8 MFMA/iter).
// XCD-clustered mapping: xcd = bid&7 sweeps all n for an 8-m-block window,
// so (A-window + full B) stays resident in that XCD's 4 MB L2.
// MODE 1: C = A@Bt+bias, f32 out, N=1024 (O-proj), grid 1024.
// MODE 2: fused Q+Lat. bid<1024: Qb@WqT+bq -> Qp bf16 (N=1024);
//         bid>=1024: Kb@WdT+bd -> Lat bf16 (N=256). grid 1280. K=1024.
// MODE 3: fused K|V: Lat@WkvT, N=2048, K=256. col<1024 -> Kp row-major
//         +bias; col>=1024 -> VpT [b][col-1024][l] +bias2. grid 2048.
// ---------------------------------------------------------------------------
template<int MODE>
__global__ __launch_bounds__(256)
void gemm64_k(const unsigned short* __restrict__ Ap, const unsigned short* __restrict__ Bt,
              const float* __restrict__ bias, void* __restrict__ Cp,
              const unsigned short* __restrict__ Ap2, const unsigned short* __restrict__ Bt2,
              const float* __restrict__ bias2, void* __restrict__ Cp2,
              int K) {
    __shared__ unsigned short As[64 * 64];   // 8 KB
    __shared__ unsigned short Bs[64 * 64];   // 8 KB

    int bid = blockIdx.x;
    const unsigned short* A;
    const unsigned short* B;
    const float* bs;
    bool second = false;
    int m0, n0;
    if (MODE == 2 && bid >= 1024) {
        bid -= 1024; A = Ap2; B = Bt2; bs = bias2; second = true;
        const int xcd = bid & 7, s = bid >> 3;          // s in [0,32)
        n0 = (s & 3) * 64; m0 = (xcd * 8 + (s >> 2)) * 64;
    } else {
        A = Ap; B = Bt; bs = bias;
        const int xcd = bid & 7, s = bid >> 3;
        if (MODE == 3) { n0 = (s & 31) * 64; m0 = (xcd * 8 + (s >> 5)) * 64; }
        else           { n0 = (s & 15) * 64; m0 = (xcd * 8 + (s >> 4)) * 64; }
    }

    const int t = threadIdx.x, lane = t & 63, wv = t >> 6;
    const int quad = lane >> 4, l15 = lane & 15;

    const int lr8 = lane >> 3;
    const int g8 = (lane & 7) ^ (lr8 & 7);
    const unsigned short* gA = A + (size_t)(m0 + wv * 16 + lr8) * K + g8 * 8;
    const unsigned short* gB = B + (size_t)(n0 + wv * 16 + lr8) * K + g8 * 8;
    unsigned short* lA = As + wv * 1024;
    unsigned short* lB = Bs + wv * 1024;

    int aoff[2][2], boff[2][2];
#pragma unroll
    for (int i = 0; i < 2; ++i) {
        const int ra = (wv >> 1) * 32 + i * 16 + l15;
        const int rb = (wv & 1) * 32 + i * 16 + l15;
#pragma unroll
        for (int ks = 0; ks < 2; ++ks) {
            aoff[i][ks] = ra * 64 + (((ks * 4 + quad) ^ (ra & 7)) << 3);
            boff[i][ks] = rb * 64 + (((ks * 4 + quad) ^ (rb & 7)) << 3);
        }
    }

    f32x4 acc[2][2] = {};
    for (int kk = 0; kk < K; kk += 64) {
        __syncthreads();
        gl16(gA + kk, lA);               gl16(gA + kk + (size_t)8 * K, lA + 512);
        gl16(gB + kk, lB);               gl16(gB + kk + (size_t)8 * K, lB + 512);
        __syncthreads();
#pragma unroll
        for (int ks = 0; ks < 2; ++ks) {
            bf16x8 a[2], b[2];
#pragma unroll
            for (int i = 0; i < 2; ++i) a[i] = ld8(As + aoff[i][ks]);
#pragma unroll
            for (int j = 0; j < 2; ++j) b[j] = ld8(Bs + boff[j][ks]);
#pragma unroll
            for (int i = 0; i < 2; ++i)
#pragma unroll
                for (int j = 0; j < 2; ++j)
                    acc[i][j] = __builtin_amdgcn_mfma_f32_16x16x32_bf16(a[i], b[j], acc[i][j], 0, 0, 0);
        }
    }

#pragma unroll
    for (int j = 0; j < 2; ++j) {
        const int col = n0 + (wv & 1) * 32 + j * 16 + l15;
        const bool isV = (MODE == 3) && (col >= 1024);
        const float bvv = isV ? bias2[col - 1024] : bs[col];
#pragma unroll
        for (int i = 0; i < 2; ++i) {
            const int rowb = m0 + (wv >> 1) * 32 + i * 16 + quad * 4;
#pragma unroll
            for (int r = 0; r < 4; ++r) {
                const float v = acc[i][j][r] + bvv;
                const int row = rowb + r;
                if (MODE == 1)
                    ((float*)Cp)[(size_t)row * 1024 + col] = v;
                else if (MODE == 2) {
                    if (second) ((unsigned short*)Cp2)[(size_t)row * 256 + col] = f2bf(v);
                    else        ((unsigned short*)Cp)[(size_t)row * 1024 + col] = f2bf(v);
                } else {  // MODE 3
                    if (!isV)   ((unsigned short*)Cp)[(size_t)row * 1024 + col] = f2bf(v);
                    else        ((unsigned short*)Cp2)[((size_t)(row >> 11) * 1024 + (col - 1024)) * LL
                                                       + (row & (LL - 1))] = f2bf(v);
                }
            }
        }
    }
}

// ---------------------------------------------------------------------------
// Causal attention: 512 thr (2 groups of 4 waves), paired q-tiles (j, 31-j),
// even/odd 64-key chunk split across groups, fixed-shift softmax (additive
// partials), LDS combine per tile. Grid 512 (1-D), XCD-clustered so each
// XCD owns 4 (h,b) combos -> K/V working set 2 MB stays L2-resident.
// ---------------------------------------------------------------------------
__global__ __launch_bounds__(512)
void attn5_k(const unsigned short* __restrict__ Qp,
             const unsigned short* __restrict__ Kp,
             const unsigned short* __restrict__ VpT,
             unsigned short* __restrict__ Op) {
    __shared__ unsigned short Ks[2][4096];      // 16 KB  (also combine buffer)
    __shared__ unsigned short Vs[2][4096];      // 16 KB
    __shared__ unsigned short Ps[8][16][72];    // 18 KB

    const int t = threadIdx.x, lane = t & 63, wv = t >> 6;
    const int grp = wv >> 2, w4 = wv & 3;
    const int quad = lane >> 4, l15 = lane & 15;

    // XCD-clustered (pair, h, b): xcd = bid & 7 owns combos xcd*4 .. xcd*4+3
    const int bid = blockIdx.x;
    const int xcd = bid & 7, s = bid >> 3;      // s in [0,64)
    const int pair = s & 15;
    const int combo = xcd * 4 + (s >> 4);       // [0,32)
    const int h = combo & 15, b = combo >> 4;

    const int srow = w4 * 16 + (lane >> 3);
    const int g8 = (lane & 7) ^ ((lane >> 3) & 7);
    unsigned short* lK = &Ks[grp][w4 * 1024];
    unsigned short* lV = &Vs[grp][w4 * 1024];
    const int sw = l15 & 7;
    float* cb = (float*)&Ks[0][0];              // 20 KB combine area

    for (int tsel = 0; tsel < 2; ++tsel) {
        const int tile = tsel ? (31 - pair) : pair;
        const int q0 = tile * 64;

        const unsigned short* qp = Qp + (size_t)(b * LL + q0 + w4 * 16 + l15) * DM + h * DK;
        const bf16x8 aq0 = ld8(qp + quad * 8);
        const bf16x8 aq1 = ld8(qp + 32 + quad * 8);

        f32x4 acc[4] = {};
        float lrow[4] = {0.f, 0.f, 0.f, 0.f};
        const int rowq = q0 + w4 * 16 + quad * 4;

        const int nit = tile / 2 + 1;
        for (int it = 0; it < nit; ++it) {
            const int c = 2 * it + grp;
            const bool active = (c <= tile);
            const int kt = c * 64;
            __syncthreads();
            if (active) {
                const unsigned short* kg = Kp + (size_t)(b * LL + kt + srow) * DM + h * DK + g8 * 8;
                const unsigned short* vg = VpT + ((size_t)(b * NH + h) * DK + srow) * LL + kt + g8 * 8;
                gl16(kg, lK);             gl16(kg + (size_t)8 * DM, lK + 512);
                gl16(vg, lV);             gl16(vg + (size_t)8 * LL, lV + 512);
            }
            __syncthreads();
            if (!active) continue;

            f32x4 s4[4];
#pragma unroll
            for (int sub = 0; sub < 4; ++sub) {
                const int base = (sub * 16 + l15) * 64;
                f32x4 ss = {};
                bf16x8 b0 = ld8(&Ks[grp][base + ((quad ^ sw) << 3)]);
                ss = __builtin_amdgcn_mfma_f32_16x16x32_bf16(aq0, b0, ss, 0, 0, 0);
                bf16x8 b1 = ld8(&Ks[grp][base + (((4 + quad) ^ sw) << 3)]);
                ss = __builtin_amdgcn_mfma_f32_16x16x32_bf16(aq1, b1, ss, 0, 0, 0);
                s4[sub] = ss;
            }

            const bool diag = (c == tile);
#pragma unroll
            for (int sub = 0; sub < 4; ++sub) {
                const int col = kt + sub * 16 + l15;
#pragma unroll
                for (int r = 0; r < 4; ++r) {
                    float e = exp2f(fmaf(s4[sub][r], 0.18033688011112042f, -16.0f));
                    if (diag && col > rowq + r) e = 0.f;
                    lrow[r] += e;
                    Ps[wv][quad * 4 + r][sub * 16 + l15] =
                        (unsigned short)(__builtin_bit_cast(unsigned int, e) >> 16);
                }
            }

#pragma unroll
            for (int ks = 0; ks < 2; ++ks) {
                bf16x8 ap = ld8(&Ps[wv][l15][ks * 32 + quad * 8]);
#pragma unroll
                for (int sub = 0; sub < 4; ++sub) {
                    bf16x8 bv = ld8(&Vs[grp][(sub * 16 + l15) * 64 + (((ks * 4 + quad) ^ sw) << 3)]);
                    acc[sub] = __builtin_amdgcn_mfma_f32_16x16x32_bf16(ap, bv, acc[sub], 0, 0, 0);
                }
            }
        }

        // combine group 1 -> group 0 through LDS; group 0 finalizes + stores
        __syncthreads();
        const int base = (w4 * 64 + lane) * 20;
        if (grp == 1) {
#pragma unroll
            for (int sub = 0; sub < 4; ++sub)
#pragma unroll
                for (int r = 0; r < 4; ++r) cb[base + sub * 4 + r] = acc[sub][r];
#pragma unroll
            for (int r = 0; r < 4; ++r) cb[base + 16 + r] = lrow[r];
        }
        __syncthreads();
        if (grp == 0) {
#pragma unroll
            for (int sub = 0; sub < 4; ++sub)
#pragma unroll
                for (int r = 0; r < 4; ++r) acc[sub][r] += cb[base + sub * 4 + r];
#pragma unroll
            for (int r = 0; r < 4; ++r) {
                lrow[r] += cb[base + 16 + r];
#pragma unroll
                for (int off = 1; off < 16; off <<= 1)
                    lrow[r] += __shfl_xor(lrow[r], off, 64);
                lrow[r] = __builtin_amdgcn_rcpf(lrow[r]);
            }
#pragma unroll
            for (int sub = 0; sub < 4; ++sub)
#pragma unroll
                for (int r = 0; r < 4; ++r)
                    Op[(size_t)(b * LL + rowq + r) * DM + h * DK + sub * 16 + l15] =
                        f2bf(acc[sub][r] * lrow[r]);
        }
        // next tile's first __syncthreads gates re-use of the combine buffer
    }
}

// ---------------------------------------------------------------------------
extern "C" void kernel_launch(void* const* d_in, const int* in_sizes, int n_in,
                              void* d_out, int out_size, void* d_ws, size_t ws_size,
                              hipStream_t stream) {
    const float* queries = (const float*)d_in[0];
    const float* keys    = (const float*)d_in[1];
    const float* Wq = (const float*)d_in[3];  const float* bq = (const float*)d_in[4];
    const float* Wd = (const float*)d_in[5];  const float* bd = (const float*)d_in[6];
    const float* Wk = (const float*)d_in[7];  const float* bk = (const float*)d_in[8];
    const float* Wv = (const float*)d_in[9];  const float* bv = (const float*)d_in[10];
    const float* Wo = (const float*)d_in[11]; const float* bo = (const float*)d_in[12];

    char* ws = (char*)d_ws;
    const size_t MB = 1048576;
    unsigned short* Qp   = (unsigned short*)(ws);                   // [0,8M)
    unsigned short* Kb   = (unsigned short*)(ws + 8 * MB);          // prep->QLat
    unsigned short* Kp   = (unsigned short*)(ws + 8 * MB);          // KV->attn
    unsigned short* Qb   = (unsigned short*)(ws + 16 * MB);         // prep->QLat
    unsigned short* VpT  = (unsigned short*)(ws + 16 * MB);         // KV->attn
    unsigned short* WqT  = (unsigned short*)(ws + 24 * MB);         // prep->QLat
    unsigned short* Lat  = (unsigned short*)(ws + 26 * MB);         // QLat->KV
    unsigned short* WdT  = (unsigned short*)(ws + 28 * MB);         // prep->QLat
    unsigned short* WkvT = (unsigned short*)(ws + 28 * MB + 524288);// prep->KV
    unsigned short* Attn = (unsigned short*)(ws + 24 * MB);         // attn->O
    unsigned short* WoT  = (unsigned short*)(ws + 32 * MB);         // prep->O

    prep_k<<<4864, 256, 0, stream>>>(Wq, Wd, Wk, Wv, Wo, queries, keys,
                                     WqT, WdT, WkvT, WoT, Qb, Kb);
    gemm64_k<2><<<1280, 256, 0, stream>>>(Qb, WqT, bq, Qp, Kb, WdT, bd, Lat, 1024);
    gemm64_k<3><<<2048, 256, 0, stream>>>(Lat, WkvT, bk, Kp, nullptr, nullptr, bv, VpT, 256);
    attn5_k<<<512, 512, 0, stream>>>(Qp, Kp, VpT, Attn);
    gemm64_k<1><<<1024, 256, 0, stream>>>(Attn, WoT, bo, d_out, nullptr, nullptr, nullptr, nullptr, 1024);
}

// Round 6
// 205.459 us; speedup vs baseline: 1.8807x; 1.0193x over previous
//
#include <hip/hip_runtime.h>
#include <stdint.h>

// ---------------------------------------------------------------------------
// DS_MultiHeadLatentAttention, round 6.
// Changes vs round 5:
//  - GEMMs: 128x64 tile, BK=64 (16 MFMA : 12 ds_read : 6 gl16 per iter vs
//    8:8:4 at 64x64 -- the m92->m93 tile-size lever), grids 512-1024 blocks,
//    XCD-clustered m-windows (A-window + full B <= 3 MB per XCD L2).
//  - V-output epilogue: LDS transpose -> coalesced 64B/thread stores
//    (was 2B stores at 4KB stride).
//  - attn: causal mask hoisted into wave-uniform diag branch.
// Dispatches: prep, gemmQLat(640), gemmKV(1024), attn(512), gemmO(512).
// Workspace (34 MB, time-phased):
//   [0,8M)   Qp      [8,16M)  Kb -> Kp      [16,24M) Qb -> VpT
//   [24,32M) WqT(2M)|Lat(2M)|WdT(.5M)|WkvT(1M) -> Attn
//   [32,34M) WoT
// ---------------------------------------------------------------------------

#define DM 1024
#define NH 16
#define DK 64
#define LL 2048

typedef float  f32x4  __attribute__((ext_vector_type(4)));
typedef __bf16 bf16x8 __attribute__((ext_vector_type(8)));
typedef short  s16x8  __attribute__((ext_vector_type(8)));

__device__ __forceinline__ unsigned short f2bf(float f) {
    union { float f; unsigned int u; } v; v.f = f;
    return (unsigned short)((v.u + 0x7fffu + ((v.u >> 16) & 1u)) >> 16);
}
__device__ __forceinline__ unsigned int pack2(float a, float b) {
    return (unsigned int)f2bf(a) | ((unsigned int)f2bf(b) << 16);
}
__device__ __forceinline__ bf16x8 ld8(const unsigned short* p) {
    s16x8 s = *(const s16x8*)p;
    return __builtin_bit_cast(bf16x8, s);
}
__device__ __forceinline__ void gl16(const void* g, void* l) {
    __builtin_amdgcn_global_load_lds((__attribute__((address_space(1))) void*)(g),
                                     (__attribute__((address_space(3))) void*)(l),
                                     16, 0, 0);
}

// ---------------------------------------------------------------------------
// prep: 5 weight transposes (fp32 [K][N] -> bf16 [N][K]) + queries/keys
// fp32 -> bf16. Grid = 4864.
// ---------------------------------------------------------------------------
__global__ __launch_bounds__(256)
void prep_k(const float* __restrict__ Wq, const float* __restrict__ Wd,
            const float* __restrict__ Wk, const float* __restrict__ Wv,
            const float* __restrict__ Wo, const float* __restrict__ queries,
            const float* __restrict__ keys,
            unsigned short* __restrict__ WqT, unsigned short* __restrict__ WdT,
            unsigned short* __restrict__ WkvT, unsigned short* __restrict__ WoT,
            unsigned short* __restrict__ Qb, unsigned short* __restrict__ Kb) {
    int bid = blockIdx.x;
    const int t = threadIdx.x;

    const float* W; unsigned short* WT; int TK, TN;
    if (bid < 1024)      { W = Wq; WT = WqT;  TK = 1024; TN = 1024; }
    else if (bid < 1280) { bid -= 1024; W = Wd; WT = WdT; TK = 1024; TN = 256; }
    else if (bid < 1536) { bid -= 1280; W = Wk; WT = WkvT; TK = 256; TN = 1024; }
    else if (bid < 1792) { bid -= 1536; W = Wv; WT = WkvT + (size_t)1024 * 256; TK = 256; TN = 1024; }
    else if (bid < 2816) { bid -= 1792; W = Wo; WT = WoT;  TK = 1024; TN = 1024; }
    else {
        bid -= 2816;
        const float* src; unsigned short* dst;
        if (bid < 1024) { src = queries; dst = Qb; }
        else            { bid -= 1024; src = keys; dst = Kb; }
        const size_t base = (size_t)bid * 4096;
#pragma unroll
        for (int i = 0; i < 4; ++i) {
            float4 f = *(const float4*)(src + base + (size_t)(i * 256 + t) * 4);
            uint2 u = { pack2(f.x, f.y), pack2(f.z, f.w) };
            *(uint2*)(dst + base + (size_t)(i * 256 + t) * 4) = u;
        }
        return;
    }
    __shared__ float tile[32][33];
    const int tx = t & 31, ty = t >> 5;
    const int bx = bid % (TK / 32), by = bid / (TK / 32);
    const int k0 = bx * 32, n0 = by * 32;
#pragma unroll
    for (int i = 0; i < 4; ++i)
        tile[ty + 8 * i][tx] = W[(size_t)(k0 + ty + 8 * i) * TN + n0 + tx];
    __syncthreads();
#pragma unroll
    for (int i = 0; i < 4; ++i)
        WT[(size_t)(n0 + ty + 8 * i) * TK + k0 + tx] = f2bf(tile[tx][ty + 8 * i]);
}

// ---------------------------------------------------------------------------
// GEMM 128(M) x 64(N) tile, BK=64, 4 waves 2x2 (wave = 64m x 32n, 4x2 accs).
// XCD-clustered: xcd = bid&7 sweeps all n over a small m-window.
// MODE 0: fused Q+Lat (K=1024). bid<512: Qb@WqT+bq -> Qp bf16 [row*1024].
//         bid>=512 (128 blocks): Kb@WdT+bd -> Lat bf16 [row*256].
// MODE 1: Attn@WoT+bo -> f32 [row*1024]. grid 512, K=1024.
// MODE 2: fused K|V (K=256, N=2048): col<1024 -> Kp bf16 [row*1024];
//         col>=1024 -> VpT [b][col-1024][l] via LDS-transposed epilogue.
// ---------------------------------------------------------------------------
template<int MODE>
__global__ __launch_bounds__(256)
void gemm_k(const unsigned short* __restrict__ Ap, const unsigned short* __restrict__ Bt,
            const float* __restrict__ bias, void* __restrict__ Cp,
            const unsigned short* __restrict__ Ap2, const unsigned short* __restrict__ Bt2,
            const float* __restrict__ bias2, void* __restrict__ Cp2,
            int K) {
    __shared__ unsigned short Sh[12288];      // As 128x64 (16KB) + Bs 64x64 (8KB)
    unsigned short* As = Sh;
    unsigned short* Bs = Sh + 8192;

    int bid = blockIdx.x;
    const unsigned short* A;
    const unsigned short* B;
    const float* bs;
    bool second = false;
    int m0, n0;
    if (MODE == 0 && bid >= 512) {            // Lat part: 128 blocks, N=256
        bid -= 512; A = Ap2; B = Bt2; bs = bias2; second = true;
        const int xcd = bid & 7, s = bid >> 3;            // s in [0,16)
        n0 = (s & 3) * 64; m0 = (xcd * 4 + (s >> 2)) * 128;
    } else {
        A = Ap; B = Bt; bs = bias;
        const int xcd = bid & 7, s = bid >> 3;
        if (MODE == 2) { n0 = (s & 31) * 64; m0 = (xcd * 4 + (s >> 5)) * 128; }
        else           { n0 = (s & 15) * 64; m0 = (xcd * 4 + (s >> 4)) * 128; }
    }

    const int t = threadIdx.x, lane = t & 63, wv = t >> 6;
    const int quad = lane >> 4, l15 = lane & 15;

    const int lr8 = lane >> 3;                 // 0..7
    const int g8 = (lane & 7) ^ (lr8 & 7);     // swizzled k-chunk
    const unsigned short* gA = A + (size_t)(m0 + wv * 32 + lr8) * K + g8 * 8;
    const unsigned short* gB = B + (size_t)(n0 + wv * 16 + lr8) * K + g8 * 8;
    unsigned short* lA = As + wv * 2048;       // 32 rows/wave
    unsigned short* lB = Bs + wv * 1024;       // 16 rows/wave

    int aoff[4][2], boff[2][2];
#pragma unroll
    for (int i = 0; i < 4; ++i) {
        const int ra = (wv >> 1) * 64 + i * 16 + l15;
#pragma unroll
        for (int ks = 0; ks < 2; ++ks)
            aoff[i][ks] = ra * 64 + (((ks * 4 + quad) ^ (ra & 7)) << 3);
    }
#pragma unroll
    for (int j = 0; j < 2; ++j) {
        const int rb = (wv & 1) * 32 + j * 16 + l15;
#pragma unroll
        for (int ks = 0; ks < 2; ++ks)
            boff[j][ks] = rb * 64 + (((ks * 4 + quad) ^ (rb & 7)) << 3);
    }

    f32x4 acc[4][2] = {};
    for (int kk = 0; kk < K; kk += 64) {
        __syncthreads();
#pragma unroll
        for (int s = 0; s < 4; ++s) gl16(gA + kk + (size_t)s * 8 * K, lA + s * 512);
#pragma unroll
        for (int s = 0; s < 2; ++s) gl16(gB + kk + (size_t)s * 8 * K, lB + s * 512);
        __syncthreads();
#pragma unroll
        for (int ks = 0; ks < 2; ++ks) {
            bf16x8 a[4], b[2];
#pragma unroll
            for (int i = 0; i < 4; ++i) a[i] = ld8(As + aoff[i][ks]);
#pragma unroll
            for (int j = 0; j < 2; ++j) b[j] = ld8(Bs + boff[j][ks]);
#pragma unroll
            for (int i = 0; i < 4; ++i)
#pragma unroll
                for (int j = 0; j < 2; ++j)
                    acc[i][j] = __builtin_amdgcn_mfma_f32_16x16x32_bf16(a[i], b[j], acc[i][j], 0, 0, 0);
        }
    }

    const bool isV = (MODE == 2) && (n0 >= 1024);
    if (!isV) {
#pragma unroll
        for (int j = 0; j < 2; ++j) {
            const int col = n0 + (wv & 1) * 32 + j * 16 + l15;
            const float bvv = bs[col];
            const int cstride = second ? 256 : 1024;
#pragma unroll
            for (int i = 0; i < 2; ++i) {}     // (placeholder removed below)
#pragma unroll
            for (int i = 0; i < 4; ++i) {
                const int rowb = m0 + (wv >> 1) * 64 + i * 16 + quad * 4;
#pragma unroll
                for (int r = 0; r < 4; ++r) {
                    const float v = acc[i][j][r] + bvv;
                    const int row = rowb + r;
                    if (MODE == 1)
                        ((float*)Cp)[(size_t)row * 1024 + col] = v;
                    else if (second)
                        ((unsigned short*)Cp2)[(size_t)row * 256 + col] = f2bf(v);
                    else
                        ((unsigned short*)Cp)[(size_t)row * 1024 + col] = f2bf(v);
                }
            }
        }
    } else {
        // V part: transpose 128tok x 64d tile through LDS, store coalesced
        // to VpT[(b*1024 + d)*2048 + l].  Ld layout: [d][tok], stride 136.
        __syncthreads();                        // all frag reads done; reuse Sh
        unsigned short* Ld = Sh;                // 64*136 shorts = 17408 B
#pragma unroll
        for (int j = 0; j < 2; ++j) {
            const int dloc = (wv & 1) * 32 + j * 16 + l15;
            const float bvv = bias2[(n0 - 1024) + dloc];
#pragma unroll
            for (int i = 0; i < 4; ++i) {
                const int tokb = (wv >> 1) * 64 + i * 16 + quad * 4;
#pragma unroll
                for (int r = 0; r < 4; ++r)
                    Ld[dloc * 136 + tokb + r] = f2bf(acc[i][j][r] + bvv);
            }
        }
        __syncthreads();
        const int dloc = t >> 2;                // 0..63
        const int tk0 = (t & 3) * 32;           // 0,32,64,96
        const int bb = m0 >> 11;
        unsigned short* dst = (unsigned short*)Cp2 +
            ((size_t)bb * 1024 + (n0 - 1024) + dloc) * LL + (m0 & (LL - 1)) + tk0;
        const unsigned short* srcp = Ld + dloc * 136 + tk0;
#pragma unroll
        for (int c = 0; c < 4; ++c)
            *(uint4*)(dst + c * 8) = *(const uint4*)(srcp + c * 8);
    }
}

// ---------------------------------------------------------------------------
// Causal attention: 512 thr (2 groups of 4 waves), paired q-tiles (j, 31-j),
// even/odd 64-key chunk split, fixed-shift softmax, diag-hoisted masking.
// Grid 512, XCD-clustered (each XCD owns 4 (h,b) combos).
// ---------------------------------------------------------------------------
__global__ __launch_bounds__(512)
void attn6_k(const unsigned short* __restrict__ Qp,
             const unsigned short* __restrict__ Kp,
             const unsigned short* __restrict__ VpT,
             unsigned short* __restrict__ Op) {
    __shared__ unsigned short Ks[2][4096];
    __shared__ unsigned short Vs[2][4096];
    __shared__ unsigned short Ps[8][16][72];

    const int t = threadIdx.x, lane = t & 63, wv = t >> 6;
    const int grp = wv >> 2, w4 = wv & 3;
    const int quad = lane >> 4, l15 = lane & 15;

    const int bid = blockIdx.x;
    const int xcd = bid & 7, s = bid >> 3;
    const int pair = s & 15;
    const int combo = xcd * 4 + (s >> 4);
    const int h = combo & 15, b = combo >> 4;

    const int srow = w4 * 16 + (lane >> 3);
    const int g8 = (lane & 7) ^ ((lane >> 3) & 7);
    unsigned short* lK = &Ks[grp][w4 * 1024];
    unsigned short* lV = &Vs[grp][w4 * 1024];
    const int sw = l15 & 7;
    float* cb = (float*)&Ks[0][0];

    for (int tsel = 0; tsel < 2; ++tsel) {
        const int tile = tsel ? (31 - pair) : pair;
        const int q0 = tile * 64;

        const unsigned short* qp = Qp + (size_t)(b * LL + q0 + w4 * 16 + l15) * DM + h * DK;
        const bf16x8 aq0 = ld8(qp + quad * 8);
        const bf16x8 aq1 = ld8(qp + 32 + quad * 8);

        f32x4 acc[4] = {};
        float lrow[4] = {0.f, 0.f, 0.f, 0.f};
        const int rowq = q0 + w4 * 16 + quad * 4;

        const int nit = tile / 2 + 1;
        for (int it = 0; it < nit; ++it) {
            const int c = 2 * it + grp;
            const bool active = (c <= tile);
            const int kt = c * 64;
            __syncthreads();
            if (active) {
                const unsigned short* kg = Kp + (size_t)(b * LL + kt + srow) * DM + h * DK + g8 * 8;
                const unsigned short* vg = VpT + ((size_t)(b * NH + h) * DK + srow) * LL + kt + g8 * 8;
                gl16(kg, lK);             gl16(kg + (size_t)8 * DM, lK + 512);
                gl16(vg, lV);             gl16(vg + (size_t)8 * LL, lV + 512);
            }
            __syncthreads();
            if (!active) continue;

            f32x4 s4[4];
#pragma unroll
            for (int sub = 0; sub < 4; ++sub) {
                const int base = (sub * 16 + l15) * 64;
                f32x4 ss = {};
                bf16x8 b0 = ld8(&Ks[grp][base + ((quad ^ sw) << 3)]);
                ss = __builtin_amdgcn_mfma_f32_16x16x32_bf16(aq0, b0, ss, 0, 0, 0);
                bf16x8 b1 = ld8(&Ks[grp][base + (((4 + quad) ^ sw) << 3)]);
                ss = __builtin_amdgcn_mfma_f32_16x16x32_bf16(aq1, b1, ss, 0, 0, 0);
                s4[sub] = ss;
            }

            if (c == tile) {                   // diagonal chunk: mask
#pragma unroll
                for (int sub = 0; sub < 4; ++sub) {
                    const int col = kt + sub * 16 + l15;
#pragma unroll
                    for (int r = 0; r < 4; ++r) {
                        float e = exp2f(fmaf(s4[sub][r], 0.18033688011112042f, -16.0f));
                        if (col > rowq + r) e = 0.f;
                        lrow[r] += e;
                        Ps[wv][quad * 4 + r][sub * 16 + l15] =
                            (unsigned short)(__builtin_bit_cast(unsigned int, e) >> 16);
                    }
                }
            } else {                           // interior: no mask
#pragma unroll
                for (int sub = 0; sub < 4; ++sub) {
#pragma unroll
                    for (int r = 0; r < 4; ++r) {
                        float e = exp2f(fmaf(s4[sub][r], 0.18033688011112042f, -16.0f));
                        lrow[r] += e;
                        Ps[wv][quad * 4 + r][sub * 16 + l15] =
                            (unsigned short)(__builtin_bit_cast(unsigned int, e) >> 16);
                    }
                }
            }

#pragma unroll
            for (int ks = 0; ks < 2; ++ks) {
                bf16x8 ap = ld8(&Ps[wv][l15][ks * 32 + quad * 8]);
#pragma unroll
                for (int sub = 0; sub < 4; ++sub) {
                    bf16x8 bv = ld8(&Vs[grp][(sub * 16 + l15) * 64 + (((ks * 4 + quad) ^ sw) << 3)]);
                    acc[sub] = __builtin_amdgcn_mfma_f32_16x16x32_bf16(ap, bv, acc[sub], 0, 0, 0);
                }
            }
        }

        __syncthreads();
        const int base = (w4 * 64 + lane) * 20;
        if (grp == 1) {
#pragma unroll
            for (int sub = 0; sub < 4; ++sub)
#pragma unroll
                for (int r = 0; r < 4; ++r) cb[base + sub * 4 + r] = acc[sub][r];
#pragma unroll
            for (int r = 0; r < 4; ++r) cb[base + 16 + r] = lrow[r];
        }
        __syncthreads();
        if (grp == 0) {
#pragma unroll
            for (int sub = 0; sub < 4; ++sub)
#pragma unroll
                for (int r = 0; r < 4; ++r) acc[sub][r] += cb[base + sub * 4 + r];
#pragma unroll
            for (int r = 0; r < 4; ++r) {
                lrow[r] += cb[base + 16 + r];
#pragma unroll
                for (int off = 1; off < 16; off <<= 1)
                    lrow[r] += __shfl_xor(lrow[r], off, 64);
                lrow[r] = __builtin_amdgcn_rcpf(lrow[r]);
            }
#pragma unroll
            for (int sub = 0; sub < 4; ++sub)
#pragma unroll
                for (int r = 0; r < 4; ++r)
                    Op[(size_t)(b * LL + rowq + r) * DM + h * DK + sub * 16 + l15] =
                        f2bf(acc[sub][r] * lrow[r]);
        }
    }
}

// ---------------------------------------------------------------------------
extern "C" void kernel_launch(void* const* d_in, const int* in_sizes, int n_in,
                              void* d_out, int out_size, void* d_ws, size_t ws_size,
                              hipStream_t stream) {
    const float* queries = (const float*)d_in[0];
    const float* keys    = (const float*)d_in[1];
    const float* Wq = (const float*)d_in[3];  const float* bq = (const float*)d_in[4];
    const float* Wd = (const float*)d_in[5];  const float* bd = (const float*)d_in[6];
    const float* Wk = (const float*)d_in[7];  const float* bk = (const float*)d_in[8];
    const float* Wv = (const float*)d_in[9];  const float* bv = (const float*)d_in[10];
    const float* Wo = (const float*)d_in[11]; const float* bo = (const float*)d_in[12];

    char* ws = (char*)d_ws;
    const size_t MB = 1048576;
    unsigned short* Qp   = (unsigned short*)(ws);
    unsigned short* Kb   = (unsigned short*)(ws + 8 * MB);
    unsigned short* Kp   = (unsigned short*)(ws + 8 * MB);
    unsigned short* Qb   = (unsigned short*)(ws + 16 * MB);
    unsigned short* VpT  = (unsigned short*)(ws + 16 * MB);
    unsigned short* WqT  = (unsigned short*)(ws + 24 * MB);
    unsigned short* Lat  = (unsigned short*)(ws + 26 * MB);
    unsigned short* WdT  = (unsigned short*)(ws + 28 * MB);
    unsigned short* WkvT = (unsigned short*)(ws + 28 * MB + 524288);
    unsigned short* Attn = (unsigned short*)(ws + 24 * MB);
    unsigned short* WoT  = (unsigned short*)(ws + 32 * MB);

    prep_k<<<4864, 256, 0, stream>>>(Wq, Wd, Wk, Wv, Wo, queries, keys,
                                     WqT, WdT, WkvT, WoT, Qb, Kb);
    gemm_k<0><<<640, 256, 0, stream>>>(Qb, WqT, bq, Qp, Kb, WdT, bd, Lat, 1024);
    gemm_k<2><<<1024, 256, 0, stream>>>(Lat, WkvT, bk, Kp, nullptr, nullptr, bv, VpT, 256);
    attn6_k<<<512, 512, 0, stream>>>(Qp, Kp, VpT, Attn);
    gemm_k<1><<<512, 256, 0, stream>>>(Attn, WoT, bo, d_out, nullptr, nullptr, nullptr, nullptr, 1024);
}